// Round 1
// baseline (4727.980 us; speedup 1.0000x reference)
//
#include <hip/hip_runtime.h>
#include <math.h>

#define N_ROWS 100000
#define DIM    512
#define DHID   256
#define NCLS   2
#define BN     16   // rows per block in k1

// ---------------------------------------------------------------------------
// K1: fused  hid = relu(h@W1.T+b1); hnew = h + hid@W2.T + b2;
//            A_logits[c][n] = sum_k tanh(Wa[c,k]·hnew+ba)*sigmoid(Wb[c,k]·hnew+bb)*Wc[c,k] + bc[c]
// 16 rows/block, 256 threads. Weights read once per block (L2-resident, 3MB).
// LDS: sh_h 32KB + sh_hid 16KB = 48KB -> 3 blocks/CU.
// ---------------------------------------------------------------------------
__global__ __launch_bounds__(256, 2)
void k1_fused(const float* __restrict__ h,
              const float* __restrict__ W1, const float* __restrict__ b1,
              const float* __restrict__ W2, const float* __restrict__ b2,
              const float* __restrict__ Wa, const float* __restrict__ ba,
              const float* __restrict__ Wb, const float* __restrict__ bb,
              const float* __restrict__ Wc, const float* __restrict__ bc,
              float* __restrict__ hnew, float* __restrict__ A_logits)
{
    __shared__ float sh_h[BN][DIM];     // 32 KB; holds h, then hnew after P2
    __shared__ float sh_hid[BN][DHID];  // 16 KB; holds hid; reused as reduce buf in P3

    const int tid  = threadIdx.x;
    const int lane = tid & 63;
    const int wid  = tid >> 6;
    const int n0   = blockIdx.x * BN;

    // ---- P0: stage h tile (coalesced float4) ----
    {
        const float4* hsrc = (const float4*)(h + (size_t)n0 * DIM);
        float4* hdst = (float4*)&sh_h[0][0];
        #pragma unroll
        for (int i = 0; i < 8; ++i)
            hdst[tid + 256 * i] = hsrc[tid + 256 * i];
    }
    __syncthreads();

    // ---- P1: hid = relu(h @ W1^T + b1) ; thread: 1 col x 16 rows ----
    {
        const int col = wid * 64 + lane;                 // 0..255
        float acc[BN];
        #pragma unroll
        for (int r = 0; r < BN; ++r) acc[r] = 0.f;
        const float4* wrow = (const float4*)(W1 + (size_t)col * DIM);
        const float4* hh   = (const float4*)&sh_h[0][0]; // row stride 128 float4
        for (int kk = 0; kk < DIM / 4; ++kk) {
            float4 w = wrow[kk];
            #pragma unroll
            for (int r = 0; r < BN; ++r) {
                float4 hv = hh[r * 128 + kk];            // wave-uniform broadcast
                acc[r] += w.x * hv.x + w.y * hv.y + w.z * hv.z + w.w * hv.w;
            }
        }
        const float bias = b1[col];
        #pragma unroll
        for (int r = 0; r < BN; ++r) {
            float v = acc[r] + bias;
            sh_hid[r][col] = v > 0.f ? v : 0.f;
        }
    }
    __syncthreads();

    // ---- P2: hnew = h + hid @ W2^T + b2 ; thread: 2 cols x 16 rows ----
    {
        const int c0 = wid * 128 + lane;                 // cols c0 and c0+64
        float acc0[BN], acc1[BN];
        #pragma unroll
        for (int r = 0; r < BN; ++r) { acc0[r] = 0.f; acc1[r] = 0.f; }
        const float4* w0 = (const float4*)(W2 + (size_t)c0 * DHID);
        const float4* w1 = (const float4*)(W2 + (size_t)(c0 + 64) * DHID);
        const float4* hh = (const float4*)&sh_hid[0][0]; // row stride 64 float4
        for (int kk = 0; kk < DHID / 4; ++kk) {
            float4 wa_ = w0[kk];
            float4 wb_ = w1[kk];
            #pragma unroll
            for (int r = 0; r < BN; ++r) {
                float4 hv = hh[r * 64 + kk];             // wave-uniform broadcast
                acc0[r] += wa_.x * hv.x + wa_.y * hv.y + wa_.z * hv.z + wa_.w * hv.w;
                acc1[r] += wb_.x * hv.x + wb_.y * hv.y + wb_.z * hv.z + wb_.w * hv.w;
            }
        }
        const float bias0 = b2[c0], bias1 = b2[c0 + 64];
        #pragma unroll
        for (int r = 0; r < BN; ++r) {
            float v0 = sh_h[r][c0]      + acc0[r] + bias0;
            float v1 = sh_h[r][c0 + 64] + acc1[r] + bias1;
            hnew[(size_t)(n0 + r) * DIM + c0]      = v0;
            hnew[(size_t)(n0 + r) * DIM + c0 + 64] = v1;
            sh_h[r][c0]      = v0;   // element-exclusive in-place update
            sh_h[r][c0 + 64] = v1;
        }
    }
    __syncthreads();

    // ---- P3: gated attention logits ; thread: 1 k-col x 16 rows, loop classes ----
    {
        float* sh_red = &sh_hid[0][0];                   // reuse (16*4 floats)
        const int col = wid * 64 + lane;                 // 0..255 (k index)
        for (int c = 0; c < NCLS; ++c) {
            float aacc[BN], gacc[BN];
            #pragma unroll
            for (int r = 0; r < BN; ++r) { aacc[r] = 0.f; gacc[r] = 0.f; }
            const float4* war = (const float4*)(Wa + ((size_t)c * DHID + col) * DIM);
            const float4* wbr = (const float4*)(Wb + ((size_t)c * DHID + col) * DIM);
            const float4* hh  = (const float4*)&sh_h[0][0];
            for (int kk = 0; kk < DIM / 4; ++kk) {
                float4 wa_ = war[kk];
                float4 wb_ = wbr[kk];
                #pragma unroll
                for (int r = 0; r < BN; ++r) {
                    float4 hv = hh[r * 128 + kk];        // wave-uniform broadcast
                    aacc[r] += wa_.x * hv.x + wa_.y * hv.y + wa_.z * hv.z + wa_.w * hv.w;
                    gacc[r] += wb_.x * hv.x + wb_.y * hv.y + wb_.z * hv.z + wb_.w * hv.w;
                }
            }
            const float ba_ = ba[c * DHID + col];
            const float bb_ = bb[c * DHID + col];
            const float wc_ = Wc[c * DHID + col];
            #pragma unroll
            for (int r = 0; r < BN; ++r) {
                float a = tanhf(aacc[r] + ba_);
                float g = 1.f / (1.f + expf(-(gacc[r] + bb_)));
                float v = a * g * wc_;
                // reduce over 64 lanes (the 64 k-cols this wave owns)
                #pragma unroll
                for (int o = 1; o < 64; o <<= 1)
                    v += __shfl_xor(v, o);
                if (lane == 0) sh_red[r * 4 + wid] = v;
            }
            __syncthreads();
            if (tid < BN) {
                float s = sh_red[tid * 4 + 0] + sh_red[tid * 4 + 1]
                        + sh_red[tid * 4 + 2] + sh_red[tid * 4 + 3] + bc[c];
                A_logits[(size_t)c * N_ROWS + n0 + tid] = s;
            }
            __syncthreads();
        }
    }
}

// ---------------------------------------------------------------------------
// K2: per-class softmax over N (2 blocks x 1024 threads); also zeroes M buffer.
// ---------------------------------------------------------------------------
__global__ __launch_bounds__(1024)
void k2_softmax(const float* __restrict__ A_logits, float* __restrict__ A_out,
                float* __restrict__ Mbuf)
{
    const int c   = blockIdx.x;
    const int tid = threadIdx.x;
    __shared__ float sred[16];
    __shared__ float sbc[2];

    if (tid < DIM) Mbuf[(size_t)c * DIM + tid] = 0.f;   // zero M[c][:] for K3

    const float* L = A_logits + (size_t)c * N_ROWS;

    // pass 1: max
    float m = -1e30f;
    for (int i = tid; i < N_ROWS; i += 1024) m = fmaxf(m, L[i]);
    #pragma unroll
    for (int o = 1; o < 64; o <<= 1) m = fmaxf(m, __shfl_xor(m, o));
    if ((tid & 63) == 0) sred[tid >> 6] = m;
    __syncthreads();
    if (tid == 0) {
        float mm = sred[0];
        for (int w = 1; w < 16; ++w) mm = fmaxf(mm, sred[w]);
        sbc[0] = mm;
    }
    __syncthreads();
    m = sbc[0];

    // pass 2: sum of exp
    float s = 0.f;
    for (int i = tid; i < N_ROWS; i += 1024) s += expf(L[i] - m);
    #pragma unroll
    for (int o = 1; o < 64; o <<= 1) s += __shfl_xor(s, o);
    if ((tid & 63) == 0) sred[tid >> 6] = s;
    __syncthreads();
    if (tid == 0) {
        float ss = 0.f;
        for (int w = 0; w < 16; ++w) ss += sred[w];
        sbc[1] = 1.f / ss;
    }
    __syncthreads();
    const float inv = sbc[1];

    // pass 3: write normalized A
    for (int i = tid; i < N_ROWS; i += 1024)
        A_out[(size_t)c * N_ROWS + i] = expf(L[i] - m) * inv;
}

// ---------------------------------------------------------------------------
// K3: M[c][d] = sum_n A[c][n] * hnew[n][d]   (atomic partial sums)
// ---------------------------------------------------------------------------
__global__ __launch_bounds__(256)
void k3_pool(const float* __restrict__ A, const float* __restrict__ hnew,
             float* __restrict__ Mbuf)
{
    const int tid = threadIdx.x;
    const int d0  = tid * 2;
    const int rows_per_block = (N_ROWS + gridDim.x - 1) / gridDim.x;
    const int r0 = blockIdx.x * rows_per_block;
    const int r1 = min(r0 + rows_per_block, N_ROWS);

    float a00 = 0.f, a01 = 0.f, a10 = 0.f, a11 = 0.f;
    for (int n = r0; n < r1; ++n) {
        float w0 = A[n];
        float w1 = A[N_ROWS + n];
        float2 hv = *(const float2*)(hnew + (size_t)n * DIM + d0);
        a00 += w0 * hv.x; a01 += w0 * hv.y;
        a10 += w1 * hv.x; a11 += w1 * hv.y;
    }
    atomicAdd(&Mbuf[d0],           a00);
    atomicAdd(&Mbuf[d0 + 1],       a01);
    atomicAdd(&Mbuf[DIM + d0],     a10);
    atomicAdd(&Mbuf[DIM + d0 + 1], a11);
}

// ---------------------------------------------------------------------------
// K4: logits/softmax/argmax/features. Output layout (floats):
//   [0..1] logits, [2..3] Y_prob, [4] Y_hat, [5..200004] A, [200005..200516] features
// ---------------------------------------------------------------------------
__global__ __launch_bounds__(512)
void k4_final(const float* __restrict__ Mbuf,
              const float* __restrict__ Wclf, const float* __restrict__ bclf,
              float* __restrict__ out)
{
    __shared__ float red[16];
    const int tid  = threadIdx.x;
    const int lane = tid & 63;
    const int wid  = tid >> 6;

    float m0 = Mbuf[tid];
    float m1 = Mbuf[DIM + tid];
    float p0 = m0 * Wclf[tid];
    float p1 = m1 * Wclf[DIM + tid];
    #pragma unroll
    for (int o = 1; o < 64; o <<= 1) {
        p0 += __shfl_xor(p0, o);
        p1 += __shfl_xor(p1, o);
    }
    if (lane == 0) { red[wid] = p0; red[8 + wid] = p1; }
    __syncthreads();
    if (tid == 0) {
        float l0 = bclf[0], l1 = bclf[1];
        for (int w = 0; w < 8; ++w) { l0 += red[w]; l1 += red[8 + w]; }
        out[0] = l0; out[1] = l1;
        float mx = fmaxf(l0, l1);
        float e0 = expf(l0 - mx), e1 = expf(l1 - mx);
        float inv = 1.f / (e0 + e1);
        out[2] = e0 * inv; out[3] = e1 * inv;
        out[4] = (l1 > l0) ? 1.0f : 0.0f;   // argmax, first-index tie-break
    }
    out[5 + 2 * N_ROWS + tid] = m1;          // features = M[C-1][:]
}

// ---------------------------------------------------------------------------
extern "C" void kernel_launch(void* const* d_in, const int* in_sizes, int n_in,
                              void* d_out, int out_size, void* d_ws, size_t ws_size,
                              hipStream_t stream)
{
    const float* h    = (const float*)d_in[0];
    const float* W1   = (const float*)d_in[1];
    const float* b1   = (const float*)d_in[2];
    const float* W2   = (const float*)d_in[3];
    const float* b2   = (const float*)d_in[4];
    const float* Wa   = (const float*)d_in[5];
    const float* ba   = (const float*)d_in[6];
    const float* Wb   = (const float*)d_in[7];
    const float* bb   = (const float*)d_in[8];
    const float* Wc   = (const float*)d_in[9];
    const float* bc   = (const float*)d_in[10];
    const float* Wclf = (const float*)d_in[11];
    const float* bclf = (const float*)d_in[12];
    float* out = (float*)d_out;

    float* hnew     = (float*)d_ws;                       // N*DIM floats (204.8 MB)
    float* A_logits = hnew + (size_t)N_ROWS * DIM;        // 2*N floats
    float* Mbuf     = A_logits + 2 * (size_t)N_ROWS;      // 1024 floats
    float* A_out    = out + 5;                            // A lives in d_out directly

    k1_fused<<<N_ROWS / BN, 256, 0, stream>>>(h, W1, b1, W2, b2, Wa, ba, Wb, bb,
                                              Wc, bc, hnew, A_logits);
    k2_softmax<<<2, 1024, 0, stream>>>(A_logits, A_out, Mbuf);
    k3_pool<<<625, 256, 0, stream>>>(A_out, hnew, Mbuf);
    k4_final<<<1, 512, 0, stream>>>(Mbuf, Wclf, bclf, out);
}

// Round 3
// 964.402 us; speedup vs baseline: 4.9025x; 4.9025x over previous
//
#include <hip/hip_runtime.h>
#include <math.h>

#define N_ROWS 100000
#define DIM    512
#define DHID   256
#define NCLS   2
#define BN     32   // rows per block in k1

typedef _Float16 f16;
typedef __attribute__((ext_vector_type(8))) _Float16 f16x8;
typedef __attribute__((ext_vector_type(4))) _Float16 f16x4;
typedef __attribute__((ext_vector_type(2))) _Float16 f16x2;
typedef __attribute__((ext_vector_type(4))) float f32x4;

__device__ inline float frcp(float x){
#if __has_builtin(__builtin_amdgcn_rcpf)
    return __builtin_amdgcn_rcpf(x);
#else
    return 1.f / x;
#endif
}

// ---------------------------------------------------------------------------
// K0: convert all GEMM weights fp32 -> fp16 into workspace (same work every
// call; graph-capture safe). Element ranges: W1f[0,131072) W2f[131072,262144)
// Waf[262144,524288) Wbf[524288,786432). 768 blocks x 256 thr x 4 elems.
// ---------------------------------------------------------------------------
__global__ __launch_bounds__(256)
void k0_cvt(const float* __restrict__ W1, const float* __restrict__ W2,
            const float* __restrict__ Wa, const float* __restrict__ Wb,
            f16* __restrict__ out)
{
    int i = (blockIdx.x * 256 + threadIdx.x) * 4;
    const float* src; int off;
    if      (i < 131072) { src = W1; off = 0; }
    else if (i < 262144) { src = W2; off = 131072; }
    else if (i < 524288) { src = Wa; off = 262144; }
    else                 { src = Wb; off = 524288; }
    float4 v = *(const float4*)(src + (i - off));
    f16x4 o; o[0] = (f16)v.x; o[1] = (f16)v.y; o[2] = (f16)v.z; o[3] = (f16)v.w;
    *(f16x4*)(out + i) = o;
}

// ---------------------------------------------------------------------------
// K1: fully fused MLP + gated attention logits via fp16 MFMA 16x16x32.
// 32 rows/block, 512 threads (8 waves). LDS tiles XOR-swizzled (T2).
// MFMA frag layout (gfx950 16x16x32, measured m89/m91): A: row=l%16, k=8*(l/16)+j;
// B: col=l%16, k=8*(l/16)+j; D: col=l%16, row=4*(l/16)+reg.
// ---------------------------------------------------------------------------
#define MFMA(a,b,c) __builtin_amdgcn_mfma_f32_16x16x32_f16((a),(b),(c),0,0,0)

__global__ __launch_bounds__(512, 4)
void k1_fused(const float* __restrict__ h,
              const f16* __restrict__ W1f, const float* __restrict__ b1,
              const f16* __restrict__ W2f, const float* __restrict__ b2,
              const f16* __restrict__ Waf, const float* __restrict__ ba,
              const f16* __restrict__ Wbf, const float* __restrict__ bb,
              const float* __restrict__ Wc, const float* __restrict__ bc,
              f16* __restrict__ hnew16, float* __restrict__ A_logits)
{
    __shared__ __align__(16) f16 sh_h[BN * DIM];    // 32 KB, swizzled; h then hnew
    __shared__ __align__(16) f16 sh_hid[BN * DHID]; // 16 KB, swizzled
    __shared__ float sh_red[8 * BN];                // 1 KB

    const int tid  = threadIdx.x;
    const int lane = tid & 63;
    const int w    = tid >> 6;     // wave 0..7
    const int l16  = lane & 15;
    const int grp  = lane >> 4;    // 0..3
    const int n0   = blockIdx.x * BN;

    // swizzled element offsets (XOR 16B slot index by row&7)
    #define SWZH(row, col) ((row) * DIM  + ((col) ^ (((row) & 7) << 3)))
    #define SWZD(row, col) ((row) * DHID + ((col) ^ (((row) & 7) << 3)))

    // ---- Phase A: stage h (fp32 -> fp16, swizzled) ----
    {
        const float4* hsrc = (const float4*)(h + (size_t)n0 * DIM);
        #pragma unroll
        for (int i = 0; i < 4; ++i) {
            int c = tid + 512 * i;            // 8-elem chunk id, 0..2047
            int row = c >> 6, colb = (c & 63) * 8;
            float4 lo = hsrc[c * 2], hi = hsrc[c * 2 + 1];
            f16x8 v;
            v[0] = (f16)lo.x; v[1] = (f16)lo.y; v[2] = (f16)lo.z; v[3] = (f16)lo.w;
            v[4] = (f16)hi.x; v[5] = (f16)hi.y; v[6] = (f16)hi.z; v[7] = (f16)hi.w;
            *(f16x8*)&sh_h[SWZH(row, colb)] = v;
        }
    }
    __syncthreads();

    // ---- Phase B: hid = relu(h @ W1^T + b1); M=32 N=256 K=512 ----
    {
        f32x4 c00 = {0,0,0,0}, c01 = {0,0,0,0}, c10 = {0,0,0,0}, c11 = {0,0,0,0};
        #pragma unroll
        for (int kt = 0; kt < 16; ++kt) {
            int kc = kt * 32 + grp * 8;
            f16x8 a0 = *(const f16x8*)&sh_h[SWZH(l16,      kc)];
            f16x8 a1 = *(const f16x8*)&sh_h[SWZH(16 + l16, kc)];
            f16x8 b0 = *(const f16x8*)(W1f + (size_t)(w * 16 + l16) * DIM + kc);
            f16x8 b1v = *(const f16x8*)(W1f + (size_t)((w + 8) * 16 + l16) * DIM + kc);
            c00 = MFMA(a0, b0, c00);  c10 = MFMA(a1, b0, c10);
            c01 = MFMA(a0, b1v, c01); c11 = MFMA(a1, b1v, c11);
        }
        #pragma unroll
        for (int q = 0; q < 2; ++q) {
            int col = (w + 8 * q) * 16 + l16;
            float bias = b1[col];
            f32x4 cm0 = q ? c01 : c00, cm1 = q ? c11 : c10;
            #pragma unroll
            for (int j = 0; j < 4; ++j) {
                int r0 = grp * 4 + j;
                float v0 = cm0[j] + bias; v0 = v0 > 0.f ? v0 : 0.f;
                float v1 = cm1[j] + bias; v1 = v1 > 0.f ? v1 : 0.f;
                sh_hid[SWZD(r0,      col)] = (f16)v0;
                sh_hid[SWZD(16 + r0, col)] = (f16)v1;
            }
        }
    }
    __syncthreads();

    // ---- Phase C: hnew = h + hid @ W2^T + b2; M=32 N=512 K=256 ----
    {
        f32x4 acc[2][4];
        #pragma unroll
        for (int m = 0; m < 2; ++m)
            #pragma unroll
            for (int q = 0; q < 4; ++q) acc[m][q] = (f32x4){0,0,0,0};
        #pragma unroll
        for (int kt = 0; kt < 8; ++kt) {
            int kc = kt * 32 + grp * 8;
            f16x8 a0 = *(const f16x8*)&sh_hid[SWZD(l16,      kc)];
            f16x8 a1 = *(const f16x8*)&sh_hid[SWZD(16 + l16, kc)];
            #pragma unroll
            for (int q = 0; q < 4; ++q) {
                int nt = w + 8 * q;
                f16x8 b = *(const f16x8*)(W2f + (size_t)(nt * 16 + l16) * DHID + kc);
                acc[0][q] = MFMA(a0, b, acc[0][q]);
                acc[1][q] = MFMA(a1, b, acc[1][q]);
            }
        }
        #pragma unroll
        for (int m = 0; m < 2; ++m)
            #pragma unroll
            for (int q = 0; q < 4; ++q) {
                int col = (w + 8 * q) * 16 + l16;
                float bias = b2[col];
                #pragma unroll
                for (int j = 0; j < 4; ++j) {
                    int row = m * 16 + grp * 4 + j;
                    int so  = SWZH(row, col);
                    float hold = (float)sh_h[so];
                    float v = acc[m][q][j] + bias + hold;
                    f16 hv = (f16)v;
                    sh_h[so] = hv;                                   // in-place: element-exclusive
                    hnew16[(size_t)(n0 + row) * DIM + col] = hv;
                }
            }
    }
    __syncthreads();

    // ---- Phase D: gated attention logits per class ----
    for (int c = 0; c < NCLS; ++c) {
        f32x4 accA[2][2], accG[2][2];
        #pragma unroll
        for (int m = 0; m < 2; ++m)
            #pragma unroll
            for (int q = 0; q < 2; ++q) { accA[m][q] = (f32x4){0,0,0,0}; accG[m][q] = (f32x4){0,0,0,0}; }
        #pragma unroll
        for (int kt = 0; kt < 16; ++kt) {
            int kc = kt * 32 + grp * 8;
            f16x8 a0 = *(const f16x8*)&sh_h[SWZH(l16,      kc)];
            f16x8 a1 = *(const f16x8*)&sh_h[SWZH(16 + l16, kc)];
            #pragma unroll
            for (int q = 0; q < 2; ++q) {
                int nt = w + 8 * q;
                f16x8 bA = *(const f16x8*)(Waf + ((size_t)c * DHID + nt * 16 + l16) * DIM + kc);
                f16x8 bB = *(const f16x8*)(Wbf + ((size_t)c * DHID + nt * 16 + l16) * DIM + kc);
                accA[0][q] = MFMA(a0, bA, accA[0][q]);
                accA[1][q] = MFMA(a1, bA, accA[1][q]);
                accG[0][q] = MFMA(a0, bB, accG[0][q]);
                accG[1][q] = MFMA(a1, bB, accG[1][q]);
            }
        }
        float vsum[2][4];
        #pragma unroll
        for (int m = 0; m < 2; ++m)
            #pragma unroll
            for (int j = 0; j < 4; ++j) vsum[m][j] = 0.f;
        #pragma unroll
        for (int q = 0; q < 2; ++q) {
            int col = (w + 8 * q) * 16 + l16;
            float bav = ba[c * DHID + col];
            float bbv = bb[c * DHID + col];
            float wcv = Wc[c * DHID + col];
            #pragma unroll
            for (int m = 0; m < 2; ++m)
                #pragma unroll
                for (int j = 0; j < 4; ++j) {
                    float sa = accA[m][q][j] + bav;
                    float sg = accG[m][q][j] + bbv;
                    float ea = __expf(2.f * sa);
                    float ta = 1.f - 2.f * frcp(ea + 1.f);      // tanh
                    float sgm = frcp(1.f + __expf(-sg));        // sigmoid
                    vsum[m][j] += ta * sgm * wcv;
                }
        }
        #pragma unroll
        for (int m = 0; m < 2; ++m)
            #pragma unroll
            for (int j = 0; j < 4; ++j) {
                float v = vsum[m][j];
                v += __shfl_xor(v, 1); v += __shfl_xor(v, 2);
                v += __shfl_xor(v, 4); v += __shfl_xor(v, 8);
                if (l16 == 0) sh_red[w * BN + m * 16 + grp * 4 + j] = v;
            }
        __syncthreads();
        if (tid < BN) {
            float s = bc[c];
            #pragma unroll
            for (int ww = 0; ww < 8; ++ww) s += sh_red[ww * BN + tid];
            A_logits[(size_t)c * N_ROWS + n0 + tid] = s;
        }
        __syncthreads();
    }
    #undef SWZH
    #undef SWZD
}

// ---------------------------------------------------------------------------
// K2: per-class softmax over N (2 blocks x 1024 threads); also zeroes M buffer.
// ---------------------------------------------------------------------------
__global__ __launch_bounds__(1024)
void k2_softmax(const float* __restrict__ A_logits, float* __restrict__ A_out,
                float* __restrict__ Mbuf)
{
    const int c   = blockIdx.x;
    const int tid = threadIdx.x;
    __shared__ float sred[16];
    __shared__ float sbc[2];

    if (tid < DIM) Mbuf[(size_t)c * DIM + tid] = 0.f;

    const float* L = A_logits + (size_t)c * N_ROWS;

    float m = -1e30f;
    for (int i = tid; i < N_ROWS; i += 1024) m = fmaxf(m, L[i]);
    #pragma unroll
    for (int o = 1; o < 64; o <<= 1) m = fmaxf(m, __shfl_xor(m, o));
    if ((tid & 63) == 0) sred[tid >> 6] = m;
    __syncthreads();
    if (tid == 0) {
        float mm = sred[0];
        for (int ww = 1; ww < 16; ++ww) mm = fmaxf(mm, sred[ww]);
        sbc[0] = mm;
    }
    __syncthreads();
    m = sbc[0];

    float s = 0.f;
    for (int i = tid; i < N_ROWS; i += 1024) s += expf(L[i] - m);
    #pragma unroll
    for (int o = 1; o < 64; o <<= 1) s += __shfl_xor(s, o);
    if ((tid & 63) == 0) sred[tid >> 6] = s;
    __syncthreads();
    if (tid == 0) {
        float ss = 0.f;
        for (int ww = 0; ww < 16; ++ww) ss += sred[ww];
        sbc[1] = 1.f / ss;
    }
    __syncthreads();
    const float inv = sbc[1];

    for (int i = tid; i < N_ROWS; i += 1024)
        A_out[(size_t)c * N_ROWS + i] = expf(L[i] - m) * inv;
}

// ---------------------------------------------------------------------------
// K3: M[c][d] = sum_n A[c][n] * hnew16[n][d]  (fp16 hnew, fp32 accum, atomics)
// ---------------------------------------------------------------------------
__global__ __launch_bounds__(256)
void k3_pool(const float* __restrict__ A, const f16* __restrict__ hnew16,
             float* __restrict__ Mbuf)
{
    const int tid = threadIdx.x;
    const int d0  = tid * 2;
    const int rows_per_block = (N_ROWS + gridDim.x - 1) / gridDim.x;
    const int r0 = blockIdx.x * rows_per_block;
    const int r1 = min(r0 + rows_per_block, N_ROWS);

    float a00 = 0.f, a01 = 0.f, a10 = 0.f, a11 = 0.f;
    for (int n = r0; n < r1; ++n) {
        float w0 = A[n];
        float w1 = A[N_ROWS + n];
        f16x2 hv = *(const f16x2*)(hnew16 + (size_t)n * DIM + d0);
        float hx = (float)hv[0], hy = (float)hv[1];
        a00 += w0 * hx; a01 += w0 * hy;
        a10 += w1 * hx; a11 += w1 * hy;
    }
    atomicAdd(&Mbuf[d0],           a00);
    atomicAdd(&Mbuf[d0 + 1],       a01);
    atomicAdd(&Mbuf[DIM + d0],     a10);
    atomicAdd(&Mbuf[DIM + d0 + 1], a11);
}

// ---------------------------------------------------------------------------
// K4: logits/softmax/argmax/features. Output layout (floats):
//   [0..1] logits, [2..3] Y_prob, [4] Y_hat, [5..200004] A, [200005..200516] features
// ---------------------------------------------------------------------------
__global__ __launch_bounds__(512)
void k4_final(const float* __restrict__ Mbuf,
              const float* __restrict__ Wclf, const float* __restrict__ bclf,
              float* __restrict__ out)
{
    __shared__ float red[16];
    const int tid  = threadIdx.x;
    const int lane = tid & 63;
    const int wid  = tid >> 6;

    float m0 = Mbuf[tid];
    float m1 = Mbuf[DIM + tid];
    float p0 = m0 * Wclf[tid];
    float p1 = m1 * Wclf[DIM + tid];
    #pragma unroll
    for (int o = 1; o < 64; o <<= 1) {
        p0 += __shfl_xor(p0, o);
        p1 += __shfl_xor(p1, o);
    }
    if (lane == 0) { red[wid] = p0; red[8 + wid] = p1; }
    __syncthreads();
    if (tid == 0) {
        float l0 = bclf[0], l1 = bclf[1];
        for (int ww = 0; ww < 8; ++ww) { l0 += red[ww]; l1 += red[8 + ww]; }
        out[0] = l0; out[1] = l1;
        float mx = fmaxf(l0, l1);
        float e0 = expf(l0 - mx), e1 = expf(l1 - mx);
        float inv = 1.f / (e0 + e1);
        out[2] = e0 * inv; out[3] = e1 * inv;
        out[4] = (l1 > l0) ? 1.0f : 0.0f;
    }
    out[5 + 2 * N_ROWS + tid] = m1;          // features = M[C-1][:]
}

// ---------------------------------------------------------------------------
extern "C" void kernel_launch(void* const* d_in, const int* in_sizes, int n_in,
                              void* d_out, int out_size, void* d_ws, size_t ws_size,
                              hipStream_t stream)
{
    const float* h    = (const float*)d_in[0];
    const float* W1   = (const float*)d_in[1];
    const float* b1   = (const float*)d_in[2];
    const float* W2   = (const float*)d_in[3];
    const float* b2   = (const float*)d_in[4];
    const float* Wa   = (const float*)d_in[5];
    const float* ba   = (const float*)d_in[6];
    const float* Wb   = (const float*)d_in[7];
    const float* bb   = (const float*)d_in[8];
    const float* Wc   = (const float*)d_in[9];
    const float* bc   = (const float*)d_in[10];
    const float* Wclf = (const float*)d_in[11];
    const float* bclf = (const float*)d_in[12];
    float* out = (float*)d_out;

    // workspace layout (all 16B-aligned)
    f16*   hnew16   = (f16*)d_ws;                                  // N*512 f16 = 102.4 MB
    f16*   W1f      = (f16*)((char*)d_ws + (size_t)N_ROWS * DIM * 2);
    f16*   W2f      = W1f + 256 * 512;
    f16*   Waf      = W2f + 512 * 256;
    f16*   Wbf      = Waf + 2 * 256 * 512;
    float* A_logits = (float*)(Wbf + 2 * 256 * 512);               // 2*N f32
    float* Mbuf     = A_logits + 2 * (size_t)N_ROWS;               // 1024 f32
    float* A_out    = out + 5;

    k0_cvt<<<768, 256, 0, stream>>>(W1, W2, Wa, Wb, W1f);
    k1_fused<<<N_ROWS / BN, 512, 0, stream>>>(h, W1f, b1, W2f, b2, Waf, ba,
                                              Wbf, bb, Wc, bc, hnew16, A_logits);
    k2_softmax<<<2, 1024, 0, stream>>>(A_logits, A_out, Mbuf);
    k3_pool<<<625, 256, 0, stream>>>(A_out, hnew16, Mbuf);
    k4_final<<<1, 512, 0, stream>>>(Mbuf, Wclf, bclf, out);
}

// Round 4
// 907.333 us; speedup vs baseline: 5.2109x; 1.0629x over previous
//
#include <hip/hip_runtime.h>
#include <math.h>

#define N_ROWS 100000
#define DIM    512
#define DHID   256
#define NCLS   2
#define BN     32   // rows per block in k1
#define NCHUNK 64   // softmax partial chunks per class

typedef _Float16 f16;
typedef __attribute__((ext_vector_type(8))) _Float16 f16x8;
typedef __attribute__((ext_vector_type(4))) _Float16 f16x4;
typedef __attribute__((ext_vector_type(2))) _Float16 f16x2;
typedef __attribute__((ext_vector_type(4))) float f32x4;

__device__ inline float frcp(float x){
#if __has_builtin(__builtin_amdgcn_rcpf)
    return __builtin_amdgcn_rcpf(x);
#else
    return 1.f / x;
#endif
}

// ---------------------------------------------------------------------------
// K0: convert all GEMM weights fp32 -> fp16 into workspace.
// ---------------------------------------------------------------------------
__global__ __launch_bounds__(256)
void k0_cvt(const float* __restrict__ W1, const float* __restrict__ W2,
            const float* __restrict__ Wa, const float* __restrict__ Wb,
            f16* __restrict__ out)
{
    int i = (blockIdx.x * 256 + threadIdx.x) * 4;
    const float* src; int off;
    if      (i < 131072) { src = W1; off = 0; }
    else if (i < 262144) { src = W2; off = 131072; }
    else if (i < 524288) { src = Wa; off = 262144; }
    else                 { src = Wb; off = 524288; }
    float4 v = *(const float4*)(src + (i - off));
    f16x4 o; o[0] = (f16)v.x; o[1] = (f16)v.y; o[2] = (f16)v.z; o[3] = (f16)v.w;
    *(f16x4*)(out + i) = o;
}

// ---------------------------------------------------------------------------
// K1: fused MLP + gated attention logits via fp16 MFMA 16x16x32, with explicit
// double-buffered prefetch of A(LDS) and B(global/L2) fragments in every phase
// (R3 showed VGPR=60 -> zero pipelining -> 80% stall; this round trades ~50
// more VGPRs for load/MFMA overlap).
// Frag layout (m89/m91): A: row=l%16,k=8*(l/16)+j; B: col=l%16; D: col=l%16,row=4*(l/16)+reg.
// ---------------------------------------------------------------------------
#define MFMA(a,b,c) __builtin_amdgcn_mfma_f32_16x16x32_f16((a),(b),(c),0,0,0)

__global__ __launch_bounds__(512, 4)
void k1_fused(const float* __restrict__ h,
              const f16* __restrict__ W1f, const float* __restrict__ b1,
              const f16* __restrict__ W2f, const float* __restrict__ b2,
              const f16* __restrict__ Waf, const float* __restrict__ ba,
              const f16* __restrict__ Wbf, const float* __restrict__ bb,
              const float* __restrict__ Wc, const float* __restrict__ bc,
              f16* __restrict__ hnew16, float* __restrict__ A_logits)
{
    __shared__ __align__(16) f16 sh_h[BN * DIM];    // 32 KB swizzled; h then hnew
    __shared__ __align__(16) f16 sh_hid[BN * DHID]; // 16 KB swizzled
    __shared__ float sh_red[8 * BN];                // 1 KB

    const int tid  = threadIdx.x;
    const int lane = tid & 63;
    const int w    = tid >> 6;     // wave 0..7
    const int l16  = lane & 15;
    const int grp  = lane >> 4;    // 0..3
    const int n0   = blockIdx.x * BN;

    #define SWZH(row, col) ((row) * DIM  + ((col) ^ (((row) & 7) << 3)))
    #define SWZD(row, col) ((row) * DHID + ((col) ^ (((row) & 7) << 3)))

    // ---- Phase A: stage h (fp32 -> fp16, swizzled) ----
    {
        const float4* hsrc = (const float4*)(h + (size_t)n0 * DIM);
        #pragma unroll
        for (int i = 0; i < 4; ++i) {
            int c = tid + 512 * i;
            int row = c >> 6, colb = (c & 63) * 8;
            float4 lo = hsrc[c * 2], hi = hsrc[c * 2 + 1];
            f16x8 v;
            v[0] = (f16)lo.x; v[1] = (f16)lo.y; v[2] = (f16)lo.z; v[3] = (f16)lo.w;
            v[4] = (f16)hi.x; v[5] = (f16)hi.y; v[6] = (f16)hi.z; v[7] = (f16)hi.w;
            *(f16x8*)&sh_h[SWZH(row, colb)] = v;
        }
    }
    __syncthreads();

    // ---- Phase B: hid = relu(h @ W1^T + b1); M=32 N=256 K=512, 16 kt ----
    {
        const f16x8* B0 = (const f16x8*)(W1f + (size_t)(w * 16 + l16) * DIM);
        const f16x8* B1 = (const f16x8*)(W1f + (size_t)((w + 8) * 16 + l16) * DIM);
        f16x8 a0c = *(const f16x8*)&sh_h[SWZH(l16,      grp * 8)];
        f16x8 a1c = *(const f16x8*)&sh_h[SWZH(16 + l16, grp * 8)];
        f16x8 b0c = B0[grp], b1c = B1[grp];
        f32x4 c00 = {0,0,0,0}, c01 = {0,0,0,0}, c10 = {0,0,0,0}, c11 = {0,0,0,0};
        #pragma unroll
        for (int kt = 0; kt < 16; ++kt) {
            f16x8 a0n = a0c, a1n = a1c, b0n = b0c, b1n = b1c;
            if (kt < 15) {
                int kc = (kt + 1) * 32 + grp * 8;
                int gi = (kt + 1) * 4 + grp;
                a0n = *(const f16x8*)&sh_h[SWZH(l16,      kc)];
                a1n = *(const f16x8*)&sh_h[SWZH(16 + l16, kc)];
                b0n = B0[gi]; b1n = B1[gi];
            }
            c00 = MFMA(a0c, b0c, c00);  c10 = MFMA(a1c, b0c, c10);
            c01 = MFMA(a0c, b1c, c01);  c11 = MFMA(a1c, b1c, c11);
            a0c = a0n; a1c = a1n; b0c = b0n; b1c = b1n;
        }
        #pragma unroll
        for (int q = 0; q < 2; ++q) {
            int col = (w + 8 * q) * 16 + l16;
            float bias = b1[col];
            f32x4 cm0 = q ? c01 : c00, cm1 = q ? c11 : c10;
            #pragma unroll
            for (int j = 0; j < 4; ++j) {
                int r0 = grp * 4 + j;
                float v0 = cm0[j] + bias; v0 = v0 > 0.f ? v0 : 0.f;
                float v1 = cm1[j] + bias; v1 = v1 > 0.f ? v1 : 0.f;
                sh_hid[SWZD(r0,      col)] = (f16)v0;
                sh_hid[SWZD(16 + r0, col)] = (f16)v1;
            }
        }
    }
    __syncthreads();

    // ---- Phase C: hnew = h + hid @ W2^T + b2; M=32 N=512 K=256, 8 kt ----
    {
        const f16x8* P0 = (const f16x8*)(W2f + (size_t)((w     ) * 16 + l16) * DHID);
        const f16x8* P1 = (const f16x8*)(W2f + (size_t)((w +  8) * 16 + l16) * DHID);
        const f16x8* P2 = (const f16x8*)(W2f + (size_t)((w + 16) * 16 + l16) * DHID);
        const f16x8* P3 = (const f16x8*)(W2f + (size_t)((w + 24) * 16 + l16) * DHID);
        f32x4 acc[2][4];
        #pragma unroll
        for (int m = 0; m < 2; ++m)
            #pragma unroll
            for (int q = 0; q < 4; ++q) acc[m][q] = (f32x4){0,0,0,0};
        f16x8 a0c = *(const f16x8*)&sh_hid[SWZD(l16,      grp * 8)];
        f16x8 a1c = *(const f16x8*)&sh_hid[SWZD(16 + l16, grp * 8)];
        f16x8 b0c = P0[grp], b1c = P1[grp], b2c = P2[grp], b3c = P3[grp];
        #pragma unroll
        for (int kt = 0; kt < 8; ++kt) {
            f16x8 a0n = a0c, a1n = a1c, b0n = b0c, b1n = b1c, b2n = b2c, b3n = b3c;
            if (kt < 7) {
                int kc = (kt + 1) * 32 + grp * 8;
                int gi = (kt + 1) * 4 + grp;
                a0n = *(const f16x8*)&sh_hid[SWZD(l16,      kc)];
                a1n = *(const f16x8*)&sh_hid[SWZD(16 + l16, kc)];
                b0n = P0[gi]; b1n = P1[gi]; b2n = P2[gi]; b3n = P3[gi];
            }
            acc[0][0] = MFMA(a0c, b0c, acc[0][0]); acc[1][0] = MFMA(a1c, b0c, acc[1][0]);
            acc[0][1] = MFMA(a0c, b1c, acc[0][1]); acc[1][1] = MFMA(a1c, b1c, acc[1][1]);
            acc[0][2] = MFMA(a0c, b2c, acc[0][2]); acc[1][2] = MFMA(a1c, b2c, acc[1][2]);
            acc[0][3] = MFMA(a0c, b3c, acc[0][3]); acc[1][3] = MFMA(a1c, b3c, acc[1][3]);
            a0c = a0n; a1c = a1n; b0c = b0n; b1c = b1n; b2c = b2n; b3c = b3n;
        }
        #pragma unroll
        for (int m = 0; m < 2; ++m)
            #pragma unroll
            for (int q = 0; q < 4; ++q) {
                int col = (w + 8 * q) * 16 + l16;
                float bias = b2[col];
                #pragma unroll
                for (int j = 0; j < 4; ++j) {
                    int row = m * 16 + grp * 4 + j;
                    int so  = SWZH(row, col);
                    float hold = (float)sh_h[so];
                    float v = acc[m][q][j] + bias + hold;
                    f16 hv = (f16)v;
                    sh_h[so] = hv;                       // element-exclusive in-place
                    hnew16[(size_t)(n0 + row) * DIM + col] = hv;
                }
            }
    }
    __syncthreads();

    // ---- Phase D: gated attention logits per class; 16 kt, 8 MFMA/kt ----
    for (int c = 0; c < NCLS; ++c) {
        const f16x8* PA0 = (const f16x8*)(Waf + ((size_t)c * DHID + (w    ) * 16 + l16) * DIM);
        const f16x8* PA1 = (const f16x8*)(Waf + ((size_t)c * DHID + (w + 8) * 16 + l16) * DIM);
        const f16x8* PB0 = (const f16x8*)(Wbf + ((size_t)c * DHID + (w    ) * 16 + l16) * DIM);
        const f16x8* PB1 = (const f16x8*)(Wbf + ((size_t)c * DHID + (w + 8) * 16 + l16) * DIM);
        f32x4 aA[2][2], aG[2][2];
        #pragma unroll
        for (int m = 0; m < 2; ++m)
            #pragma unroll
            for (int q = 0; q < 2; ++q) { aA[m][q] = (f32x4){0,0,0,0}; aG[m][q] = (f32x4){0,0,0,0}; }
        f16x8 a0c = *(const f16x8*)&sh_h[SWZH(l16,      grp * 8)];
        f16x8 a1c = *(const f16x8*)&sh_h[SWZH(16 + l16, grp * 8)];
        f16x8 bA0c = PA0[grp], bA1c = PA1[grp], bB0c = PB0[grp], bB1c = PB1[grp];
        #pragma unroll
        for (int kt = 0; kt < 16; ++kt) {
            f16x8 a0n = a0c, a1n = a1c;
            f16x8 bA0n = bA0c, bA1n = bA1c, bB0n = bB0c, bB1n = bB1c;
            if (kt < 15) {
                int kc = (kt + 1) * 32 + grp * 8;
                int gi = (kt + 1) * 4 + grp;
                a0n = *(const f16x8*)&sh_h[SWZH(l16,      kc)];
                a1n = *(const f16x8*)&sh_h[SWZH(16 + l16, kc)];
                bA0n = PA0[gi]; bA1n = PA1[gi]; bB0n = PB0[gi]; bB1n = PB1[gi];
            }
            aA[0][0] = MFMA(a0c, bA0c, aA[0][0]); aA[1][0] = MFMA(a1c, bA0c, aA[1][0]);
            aA[0][1] = MFMA(a0c, bA1c, aA[0][1]); aA[1][1] = MFMA(a1c, bA1c, aA[1][1]);
            aG[0][0] = MFMA(a0c, bB0c, aG[0][0]); aG[1][0] = MFMA(a1c, bB0c, aG[1][0]);
            aG[0][1] = MFMA(a0c, bB1c, aG[0][1]); aG[1][1] = MFMA(a1c, bB1c, aG[1][1]);
            a0c = a0n; a1c = a1n; bA0c = bA0n; bA1c = bA1n; bB0c = bB0n; bB1c = bB1n;
        }
        float vsum[2][4];
        #pragma unroll
        for (int m = 0; m < 2; ++m)
            #pragma unroll
            for (int j = 0; j < 4; ++j) vsum[m][j] = 0.f;
        #pragma unroll
        for (int q = 0; q < 2; ++q) {
            int col = (w + 8 * q) * 16 + l16;
            float bav = ba[c * DHID + col];
            float bbv = bb[c * DHID + col];
            float wcv = Wc[c * DHID + col];
            #pragma unroll
            for (int m = 0; m < 2; ++m)
                #pragma unroll
                for (int j = 0; j < 4; ++j) {
                    float sa = aA[m][q][j] + bav;
                    float sg = aG[m][q][j] + bbv;
                    float ea = __expf(2.f * sa);
                    float ta = 1.f - 2.f * frcp(ea + 1.f);      // tanh
                    float sgm = frcp(1.f + __expf(-sg));        // sigmoid
                    vsum[m][j] += ta * sgm * wcv;
                }
        }
        #pragma unroll
        for (int m = 0; m < 2; ++m)
            #pragma unroll
            for (int j = 0; j < 4; ++j) {
                float v = vsum[m][j];
                v += __shfl_xor(v, 1); v += __shfl_xor(v, 2);
                v += __shfl_xor(v, 4); v += __shfl_xor(v, 8);
                if (l16 == 0) sh_red[w * BN + m * 16 + grp * 4 + j] = v;
            }
        __syncthreads();
        if (tid < BN) {
            float s = bc[c];
            #pragma unroll
            for (int ww = 0; ww < 8; ++ww) s += sh_red[ww * BN + tid];
            A_logits[(size_t)c * N_ROWS + n0 + tid] = s;
        }
        __syncthreads();
    }
    #undef SWZH
    #undef SWZD
}

// ---------------------------------------------------------------------------
// K2a: per-chunk (class, chunk) partial max + expsum. 128 blocks x 256 thr.
// ---------------------------------------------------------------------------
__global__ __launch_bounds__(256)
void k2a_partial(const float* __restrict__ A_logits, float2* __restrict__ partials)
{
    const int c     = blockIdx.x >> 6;
    const int chunk = blockIdx.x & 63;
    const int per   = (N_ROWS + NCHUNK - 1) / NCHUNK;   // 1563
    const int i0 = chunk * per;
    const int i1 = min(i0 + per, N_ROWS);
    const int tid = threadIdx.x, lane = tid & 63, w = tid >> 6;
    const float* L = A_logits + (size_t)c * N_ROWS;
    __shared__ float sm[4], ss[4];

    float m = -1e30f;
    for (int i = i0 + tid; i < i1; i += 256) m = fmaxf(m, L[i]);
    #pragma unroll
    for (int o = 1; o < 64; o <<= 1) m = fmaxf(m, __shfl_xor(m, o));
    if (lane == 0) sm[w] = m;
    __syncthreads();
    m = fmaxf(fmaxf(sm[0], sm[1]), fmaxf(sm[2], sm[3]));

    float s = 0.f;
    for (int i = i0 + tid; i < i1; i += 256) s += __expf(L[i] - m);
    #pragma unroll
    for (int o = 1; o < 64; o <<= 1) s += __shfl_xor(s, o);
    if (lane == 0) ss[w] = s;
    __syncthreads();
    if (tid == 0) {
        float2 p; p.x = m; p.y = ss[0] + ss[1] + ss[2] + ss[3];
        partials[blockIdx.x] = p;
    }
}

// ---------------------------------------------------------------------------
// K2b: combine 64 partials per class -> (M, 1/S); zero Mbuf. 1 block x 256 thr.
// wave0 = class0, wave1 = class1.
// ---------------------------------------------------------------------------
__global__ __launch_bounds__(256)
void k2b_combine(const float2* __restrict__ partials, float2* __restrict__ MS,
                 float* __restrict__ Mbuf)
{
    const int tid = threadIdx.x;
    #pragma unroll
    for (int i = 0; i < 4; ++i) Mbuf[tid + 256 * i] = 0.f;
    if (tid < 128) {
        const int c = tid >> 6, lane = tid & 63;
        float2 p = partials[c * 64 + lane];
        float M = p.x;
        #pragma unroll
        for (int o = 1; o < 64; o <<= 1) M = fmaxf(M, __shfl_xor(M, o));
        float s = p.y * __expf(p.x - M);
        #pragma unroll
        for (int o = 1; o < 64; o <<= 1) s += __shfl_xor(s, o);
        if (lane == 0) { float2 r; r.x = M; r.y = 1.f / s; MS[c] = r; }
    }
}

// ---------------------------------------------------------------------------
// K3: fused normalize + pool. A[c][n] = exp(L-M)*invS (written to out), and
// M[c][d] += sum_n A[c][n]*hnew16[n][d]. One wave reads one full 1KB row
// (f16x8 = 16B/lane). 256 blocks x 256 thr.
// ---------------------------------------------------------------------------
__global__ __launch_bounds__(256)
void k3_pool(const float* __restrict__ A_logits, const float2* __restrict__ MS,
             const f16* __restrict__ hnew16, float* __restrict__ A_out,
             float* __restrict__ Mbuf)
{
    const int tid = threadIdx.x, lane = tid & 63, w = tid >> 6;
    const int per = (N_ROWS + gridDim.x - 1) / gridDim.x;
    const int r0 = blockIdx.x * per;
    const int r1 = min(r0 + per, N_ROWS);
    const float2 ms0 = MS[0], ms1 = MS[1];
    __shared__ float red[4][2][DIM];   // 16 KB

    float acc0[8], acc1[8];
    #pragma unroll
    for (int j = 0; j < 8; ++j) { acc0[j] = 0.f; acc1[j] = 0.f; }

    for (int n = r0 + w; n < r1; n += 4) {
        float w0 = __expf(A_logits[n]          - ms0.x) * ms0.y;
        float w1 = __expf(A_logits[N_ROWS + n] - ms1.x) * ms1.y;
        if (lane == 0)      A_out[n] = w0;
        else if (lane == 1) A_out[N_ROWS + n] = w1;
        f16x8 hv = *(const f16x8*)(hnew16 + (size_t)n * DIM + lane * 8);
        #pragma unroll
        for (int j = 0; j < 8; ++j) {
            float hx = (float)hv[j];
            acc0[j] += w0 * hx;
            acc1[j] += w1 * hx;
        }
    }
    #pragma unroll
    for (int j = 0; j < 8; ++j) {
        red[w][0][lane * 8 + j] = acc0[j];
        red[w][1][lane * 8 + j] = acc1[j];
    }
    __syncthreads();
    #pragma unroll
    for (int t = 0; t < 4; ++t) {
        int idx = tid + t * 256;              // 0..1023
        int c = idx >> 9, d = idx & 511;
        float s = red[0][c][d] + red[1][c][d] + red[2][c][d] + red[3][c][d];
        atomicAdd(&Mbuf[c * DIM + d], s);
    }
}

// ---------------------------------------------------------------------------
// K4: logits/softmax/argmax/features. Output layout (floats):
//   [0..1] logits, [2..3] Y_prob, [4] Y_hat, [5..200004] A, [200005..200516] features
// ---------------------------------------------------------------------------
__global__ __launch_bounds__(512)
void k4_final(const float* __restrict__ Mbuf,
              const float* __restrict__ Wclf, const float* __restrict__ bclf,
              float* __restrict__ out)
{
    __shared__ float red[16];
    const int tid  = threadIdx.x;
    const int lane = tid & 63;
    const int wid  = tid >> 6;

    float m0 = Mbuf[tid];
    float m1 = Mbuf[DIM + tid];
    float p0 = m0 * Wclf[tid];
    float p1 = m1 * Wclf[DIM + tid];
    #pragma unroll
    for (int o = 1; o < 64; o <<= 1) {
        p0 += __shfl_xor(p0, o);
        p1 += __shfl_xor(p1, o);
    }
    if (lane == 0) { red[wid] = p0; red[8 + wid] = p1; }
    __syncthreads();
    if (tid == 0) {
        float l0 = bclf[0], l1 = bclf[1];
        for (int ww = 0; ww < 8; ++ww) { l0 += red[ww]; l1 += red[8 + ww]; }
        out[0] = l0; out[1] = l1;
        float mx = fmaxf(l0, l1);
        float e0 = expf(l0 - mx), e1 = expf(l1 - mx);
        float inv = 1.f / (e0 + e1);
        out[2] = e0 * inv; out[3] = e1 * inv;
        out[4] = (l1 > l0) ? 1.0f : 0.0f;
    }
    out[5 + 2 * N_ROWS + tid] = m1;          // features = M[C-1][:]
}

// ---------------------------------------------------------------------------
extern "C" void kernel_launch(void* const* d_in, const int* in_sizes, int n_in,
                              void* d_out, int out_size, void* d_ws, size_t ws_size,
                              hipStream_t stream)
{
    const float* h    = (const float*)d_in[0];
    const float* W1   = (const float*)d_in[1];
    const float* b1   = (const float*)d_in[2];
    const float* W2   = (const float*)d_in[3];
    const float* b2   = (const float*)d_in[4];
    const float* Wa   = (const float*)d_in[5];
    const float* ba   = (const float*)d_in[6];
    const float* Wb   = (const float*)d_in[7];
    const float* bb   = (const float*)d_in[8];
    const float* Wc   = (const float*)d_in[9];
    const float* bc   = (const float*)d_in[10];
    const float* Wclf = (const float*)d_in[11];
    const float* bclf = (const float*)d_in[12];
    float* out = (float*)d_out;

    // workspace layout (all 16B-aligned)
    f16*    hnew16   = (f16*)d_ws;                                 // 102.4 MB
    f16*    W1f      = (f16*)((char*)d_ws + (size_t)N_ROWS * DIM * 2);
    f16*    W2f      = W1f + 256 * 512;
    f16*    Waf      = W2f + 512 * 256;
    f16*    Wbf      = Waf + 2 * 256 * 512;
    float*  A_logits = (float*)(Wbf + 2 * 256 * 512);              // 2*N f32
    float*  Mbuf     = A_logits + 2 * (size_t)N_ROWS;              // 1024 f32
    float2* partials = (float2*)(Mbuf + 1024);                     // 128 float2
    float2* MS       = partials + 2 * NCHUNK;                      // 2 float2
    float*  A_out    = out + 5;

    k0_cvt<<<768, 256, 0, stream>>>(W1, W2, Wa, Wb, W1f);
    k1_fused<<<N_ROWS / BN, 512, 0, stream>>>(h, W1f, b1, W2f, b2, Waf, ba,
                                              Wbf, bb, Wc, bc, hnew16, A_logits);
    k2a_partial<<<2 * NCHUNK, 256, 0, stream>>>(A_logits, partials);
    k2b_combine<<<1, 256, 0, stream>>>(partials, MS, Mbuf);
    k3_pool<<<256, 256, 0, stream>>>(A_logits, MS, hnew16, A_out, Mbuf);
    k4_final<<<1, 512, 0, stream>>>(Mbuf, Wclf, bclf, out);
}

// Round 5
// 702.196 us; speedup vs baseline: 6.7331x; 1.2921x over previous
//
#include <hip/hip_runtime.h>
#include <math.h>

#define N_ROWS 100000
#define DIM    512
#define DHID   256
#define NCLS   2
#define BN     32   // rows per block in k1
#define NCHUNK 64   // softmax partial chunks per class

typedef _Float16 f16;
typedef __attribute__((ext_vector_type(8))) _Float16 f16x8;
typedef __attribute__((ext_vector_type(4))) _Float16 f16x4;
typedef __attribute__((ext_vector_type(2))) _Float16 f16x2;
typedef __attribute__((ext_vector_type(4))) float f32x4;

__device__ inline float frcp(float x){
#if __has_builtin(__builtin_amdgcn_rcpf)
    return __builtin_amdgcn_rcpf(x);
#else
    return 1.f / x;
#endif
}

// direct global->LDS DMA, 16B per lane (dest must be wave-uniform base + lane*16)
__device__ __forceinline__ void gll16(const f16* g, f16* l) {
    __builtin_amdgcn_global_load_lds(
        (const __attribute__((address_space(1))) void*)g,
        (__attribute__((address_space(3))) void*)l, 16, 0, 0);
}

// ---------------------------------------------------------------------------
// K0: convert all GEMM weights fp32 -> fp16 into workspace.
// ---------------------------------------------------------------------------
__global__ __launch_bounds__(256)
void k0_cvt(const float* __restrict__ W1, const float* __restrict__ W2,
            const float* __restrict__ Wa, const float* __restrict__ Wb,
            f16* __restrict__ out)
{
    int i = (blockIdx.x * 256 + threadIdx.x) * 4;
    const float* src; int off;
    if      (i < 131072) { src = W1; off = 0; }
    else if (i < 262144) { src = W2; off = 131072; }
    else if (i < 524288) { src = Wa; off = 262144; }
    else                 { src = Wb; off = 524288; }
    float4 v = *(const float4*)(src + (i - off));
    f16x4 o; o[0] = (f16)v.x; o[1] = (f16)v.y; o[2] = (f16)v.z; o[3] = (f16)v.w;
    *(f16x4*)(out + i) = o;
}

// ---------------------------------------------------------------------------
// K1: fused MLP + gated attention logits. All weight (B) operands staged into
// LDS via global_load_lds, double-buffered, 2-phase pipeline (T3-min):
//   per K-step: STAGE(next) ; ds_read frags(cur) ; MFMA ; __syncthreads.
// Every pass is 256 cols x K (Phase C and D split into 256-col sub-passes).
// B-LDS swizzle: unit(col,slot)=col*4+(slot), stored slot = s ^ ((col>>1)&3)
//  -> read slot for k-group g is grp ^ ((l16>>1)&3) (8 bank-groups, 2-way free).
// LDS: sh_h 32K + sh_hid 16K + wbuf 32K = 80K exactly -> 2 blocks/CU.
// ---------------------------------------------------------------------------
#define MFMA(a,b,c) __builtin_amdgcn_mfma_f32_16x16x32_f16((a),(b),(c),0,0,0)

__global__ __launch_bounds__(512, 4)
void k1_fused(const float* __restrict__ h,
              const f16* __restrict__ W1f, const float* __restrict__ b1,
              const f16* __restrict__ W2f, const float* __restrict__ b2,
              const f16* __restrict__ Waf, const float* __restrict__ ba,
              const f16* __restrict__ Wbf, const float* __restrict__ bb,
              const float* __restrict__ Wc, const float* __restrict__ bc,
              f16* __restrict__ hnew16, float* __restrict__ A_logits)
{
    __shared__ __align__(16) f16 sh_h[BN * DIM];    // 32 KB swizzled; h then hnew
    __shared__ __align__(16) f16 sh_hid[BN * DHID]; // 16 KB swizzled
    __shared__ __align__(16) f16 sh_wb[16384];      // 32 KB: 2 x 16KB W-slice dbuf

    const int tid  = threadIdx.x;
    const int lane = tid & 63;
    const int w    = tid >> 6;     // wave 0..7
    const int l16  = lane & 15;
    const int grp  = lane >> 4;    // 0..3
    const int n0   = blockIdx.x * BN;

    #define SWZH(row, col) ((row) * DIM  + ((col) ^ (((row) & 7) << 3)))
    #define SWZD(row, col) ((row) * DHID + ((col) ^ (((row) & 7) << 3)))

    // stage one 256-col x 32-k W-slice (16KB) into wbuf half `bufbase`
    // (elements). Source row stride KROW elems; k-base kb. 2 units/thread.
    #define STAGE_B(P, KROW, kb, bufbase)                                     \
    do {                                                                      \
        int u0 = tid;                                                         \
        int c0_ = u0 >> 2, ks0 = (u0 & 3) ^ ((u0 >> 3) & 3);                  \
        gll16((P) + (size_t)c0_ * (KROW) + (kb) + ks0 * 8,                    \
              &sh_wb[(bufbase) + u0 * 8]);                                    \
        int u1 = tid + 512;                                                   \
        int c1_ = u1 >> 2, ks1 = (u1 & 3) ^ ((u1 >> 3) & 3);                  \
        gll16((P) + (size_t)c1_ * (KROW) + (kb) + ks1 * 8,                    \
              &sh_wb[(bufbase) + u1 * 8]);                                    \
    } while (0)

    const int bslot = grp ^ ((l16 >> 1) & 3);   // read-side swizzle slot
    // B fragment for col-tile T from wbuf half `bufbase`
    #define BFRAG(bufbase, T) \
        (*(const f16x8*)&sh_wb[(bufbase) + (((T) * 16 + l16) * 4 + bslot) * 8])

    // ---- Phase A: stage h (fp32 -> fp16, swizzled) ----
    {
        const float4* hsrc = (const float4*)(h + (size_t)n0 * DIM);
        #pragma unroll
        for (int i = 0; i < 4; ++i) {
            int c = tid + 512 * i;
            int row = c >> 6, colb = (c & 63) * 8;
            float4 lo = hsrc[c * 2], hi = hsrc[c * 2 + 1];
            f16x8 v;
            v[0] = (f16)lo.x; v[1] = (f16)lo.y; v[2] = (f16)lo.z; v[3] = (f16)lo.w;
            v[4] = (f16)hi.x; v[5] = (f16)hi.y; v[6] = (f16)hi.z; v[7] = (f16)hi.w;
            *(f16x8*)&sh_h[SWZH(row, colb)] = v;
        }
    }
    STAGE_B(W1f, DIM, 0, 0);          // prologue for Phase B
    __syncthreads();

    // ---- Phase B: hid = relu(h @ W1^T + b1); 256 cols, K=512, 16 steps ----
    {
        f32x4 c00 = {0,0,0,0}, c01 = {0,0,0,0}, c10 = {0,0,0,0}, c11 = {0,0,0,0};
        #pragma unroll
        for (int kt = 0; kt < 16; ++kt) {
            const int bb = (kt & 1) * 8192;
            if (kt < 15) STAGE_B(W1f, DIM, (kt + 1) * 32, ((kt + 1) & 1) * 8192);
            int kc = kt * 32 + grp * 8;
            f16x8 a0 = *(const f16x8*)&sh_h[SWZH(l16,      kc)];
            f16x8 a1 = *(const f16x8*)&sh_h[SWZH(16 + l16, kc)];
            f16x8 b0 = BFRAG(bb, w);
            f16x8 b1v = BFRAG(bb, w + 8);
            c00 = MFMA(a0, b0, c00);  c10 = MFMA(a1, b0, c10);
            c01 = MFMA(a0, b1v, c01); c11 = MFMA(a1, b1v, c11);
            __syncthreads();
        }
        STAGE_B(W2f, DHID, 0, 0);     // prologue for Phase C half 0
        #pragma unroll
        for (int q = 0; q < 2; ++q) {
            int col = (w + 8 * q) * 16 + l16;
            float bias = b1[col];
            f32x4 cm0 = q ? c01 : c00, cm1 = q ? c11 : c10;
            #pragma unroll
            for (int j = 0; j < 4; ++j) {
                int r0 = grp * 4 + j;
                float v0 = cm0[j] + bias; v0 = v0 > 0.f ? v0 : 0.f;
                float v1 = cm1[j] + bias; v1 = v1 > 0.f ? v1 : 0.f;
                sh_hid[SWZD(r0,      col)] = (f16)v0;
                sh_hid[SWZD(16 + r0, col)] = (f16)v1;
            }
        }
        __syncthreads();
    }

    // ---- Phase C: hnew = h + hid @ W2^T + b2; 2 halves x 256 cols, K=256 ----
    #pragma unroll
    for (int half = 0; half < 2; ++half) {
        const f16* P = W2f + (size_t)half * 256 * DHID;
        // (half 0 prologue already staged above; half 1 staged at end of half 0)
        f32x4 acc[2][2];
        #pragma unroll
        for (int m = 0; m < 2; ++m)
            #pragma unroll
            for (int q = 0; q < 2; ++q) acc[m][q] = (f32x4){0,0,0,0};
        #pragma unroll
        for (int kt = 0; kt < 8; ++kt) {
            const int bb = (kt & 1) * 8192;
            if (kt < 7) STAGE_B(P, DHID, (kt + 1) * 32, ((kt + 1) & 1) * 8192);
            int kc = kt * 32 + grp * 8;
            f16x8 a0 = *(const f16x8*)&sh_hid[SWZD(l16,      kc)];
            f16x8 a1 = *(const f16x8*)&sh_hid[SWZD(16 + l16, kc)];
            f16x8 b0 = BFRAG(bb, w);
            f16x8 b1v = BFRAG(bb, w + 8);
            acc[0][0] = MFMA(a0, b0, acc[0][0]);  acc[1][0] = MFMA(a1, b0, acc[1][0]);
            acc[0][1] = MFMA(a0, b1v, acc[0][1]); acc[1][1] = MFMA(a1, b1v, acc[1][1]);
            __syncthreads();
        }
        // prologue for next pass (half1: W2 cols 256..511; after half1: Wa class0)
        if (half == 0) STAGE_B(W2f + (size_t)256 * DHID, DHID, 0, 0);
        else           STAGE_B(Waf, DIM, 0, 0);
        #pragma unroll
        for (int q = 0; q < 2; ++q) {
            int col = half * 256 + (w + 8 * q) * 16 + l16;
            float bias = b2[col];
            #pragma unroll
            for (int m = 0; m < 2; ++m)
                #pragma unroll
                for (int j = 0; j < 4; ++j) {
                    int row = m * 16 + grp * 4 + j;
                    int so  = SWZH(row, col);
                    float v = acc[m][q][j] + bias + (float)sh_h[so];
                    f16 hv = (f16)v;
                    sh_h[so] = hv;                   // element-exclusive in-place
                    hnew16[(size_t)(n0 + row) * DIM + col] = hv;
                }
        }
        __syncthreads();
    }

    // ---- Phase D: gated attention logits; per class: Wa pass + Wb pass ----
    float* sh_redf = (float*)&sh_wb[8192];   // alias wbuf[1] (barrier-separated)
    for (int c = 0; c < NCLS; ++c) {
        f32x4 aA[2][2], aG[2][2];
        #pragma unroll
        for (int m = 0; m < 2; ++m)
            #pragma unroll
            for (int q = 0; q < 2; ++q) { aA[m][q] = (f32x4){0,0,0,0}; aG[m][q] = (f32x4){0,0,0,0}; }

        const f16* PA = Waf + (size_t)c * DHID * DIM;
        const f16* PB = Wbf + (size_t)c * DHID * DIM;
        // pass 1: Wa  (prologue already staged by previous pass epilogue)
        #pragma unroll
        for (int kt = 0; kt < 16; ++kt) {
            const int bb = (kt & 1) * 8192;
            if (kt < 15) STAGE_B(PA, DIM, (kt + 1) * 32, ((kt + 1) & 1) * 8192);
            int kc = kt * 32 + grp * 8;
            f16x8 a0 = *(const f16x8*)&sh_h[SWZH(l16,      kc)];
            f16x8 a1 = *(const f16x8*)&sh_h[SWZH(16 + l16, kc)];
            f16x8 b0 = BFRAG(bb, w);
            f16x8 b1v = BFRAG(bb, w + 8);
            aA[0][0] = MFMA(a0, b0, aA[0][0]);  aA[1][0] = MFMA(a1, b0, aA[1][0]);
            aA[0][1] = MFMA(a0, b1v, aA[0][1]); aA[1][1] = MFMA(a1, b1v, aA[1][1]);
            __syncthreads();
        }
        STAGE_B(PB, DIM, 0, 0);   // prologue for Wb pass
        __syncthreads();
        // pass 2: Wb
        #pragma unroll
        for (int kt = 0; kt < 16; ++kt) {
            const int bb = (kt & 1) * 8192;
            if (kt < 15) STAGE_B(PB, DIM, (kt + 1) * 32, ((kt + 1) & 1) * 8192);
            int kc = kt * 32 + grp * 8;
            f16x8 a0 = *(const f16x8*)&sh_h[SWZH(l16,      kc)];
            f16x8 a1 = *(const f16x8*)&sh_h[SWZH(16 + l16, kc)];
            f16x8 b0 = BFRAG(bb, w);
            f16x8 b1v = BFRAG(bb, w + 8);
            aG[0][0] = MFMA(a0, b0, aG[0][0]);  aG[1][0] = MFMA(a1, b0, aG[1][0]);
            aG[0][1] = MFMA(a0, b1v, aG[0][1]); aG[1][1] = MFMA(a1, b1v, aG[1][1]);
            __syncthreads();
        }
        // epilogue: gate, weight by Wc, reduce 256 k-cols -> logit per row
        float vsum[2][4];
        #pragma unroll
        for (int m = 0; m < 2; ++m)
            #pragma unroll
            for (int j = 0; j < 4; ++j) vsum[m][j] = 0.f;
        #pragma unroll
        for (int q = 0; q < 2; ++q) {
            int col = (w + 8 * q) * 16 + l16;
            float bav = ba[c * DHID + col];
            float bbv = bb[c * DHID + col];
            float wcv = Wc[c * DHID + col];
            #pragma unroll
            for (int m = 0; m < 2; ++m)
                #pragma unroll
                for (int j = 0; j < 4; ++j) {
                    float sa = aA[m][q][j] + bav;
                    float sg = aG[m][q][j] + bbv;
                    float ea = __expf(2.f * sa);
                    float ta = 1.f - 2.f * frcp(ea + 1.f);      // tanh
                    float sgm = frcp(1.f + __expf(-sg));        // sigmoid
                    vsum[m][j] += ta * sgm * wcv;
                }
        }
        #pragma unroll
        for (int m = 0; m < 2; ++m)
            #pragma unroll
            for (int j = 0; j < 4; ++j) {
                float v = vsum[m][j];
                v += __shfl_xor(v, 1); v += __shfl_xor(v, 2);
                v += __shfl_xor(v, 4); v += __shfl_xor(v, 8);
                if (l16 == 0) sh_redf[w * BN + m * 16 + grp * 4 + j] = v;
            }
        __syncthreads();
        if (tid < BN) {
            float s = bc[c];
            #pragma unroll
            for (int ww = 0; ww < 8; ++ww) s += sh_redf[ww * BN + tid];
            A_logits[(size_t)c * N_ROWS + n0 + tid] = s;
        }
        __syncthreads();
        if (c == 0) { STAGE_B(Waf + (size_t)DHID * DIM, DIM, 0, 0); __syncthreads(); }
    }
    #undef SWZH
    #undef SWZD
    #undef STAGE_B
    #undef BFRAG
}

// ---------------------------------------------------------------------------
// K2a: per-chunk (class, chunk) partial max + expsum. 128 blocks x 256 thr.
// ---------------------------------------------------------------------------
__global__ __launch_bounds__(256)
void k2a_partial(const float* __restrict__ A_logits, float2* __restrict__ partials)
{
    const int c     = blockIdx.x >> 6;
    const int chunk = blockIdx.x & 63;
    const int per   = (N_ROWS + NCHUNK - 1) / NCHUNK;   // 1563
    const int i0 = chunk * per;
    const int i1 = min(i0 + per, N_ROWS);
    const int tid = threadIdx.x, lane = tid & 63, w = tid >> 6;
    const float* L = A_logits + (size_t)c * N_ROWS;
    __shared__ float sm[4], ss[4];

    float m = -1e30f;
    for (int i = i0 + tid; i < i1; i += 256) m = fmaxf(m, L[i]);
    #pragma unroll
    for (int o = 1; o < 64; o <<= 1) m = fmaxf(m, __shfl_xor(m, o));
    if (lane == 0) sm[w] = m;
    __syncthreads();
    m = fmaxf(fmaxf(sm[0], sm[1]), fmaxf(sm[2], sm[3]));

    float s = 0.f;
    for (int i = i0 + tid; i < i1; i += 256) s += __expf(L[i] - m);
    #pragma unroll
    for (int o = 1; o < 64; o <<= 1) s += __shfl_xor(s, o);
    if (lane == 0) ss[w] = s;
    __syncthreads();
    if (tid == 0) {
        float2 p; p.x = m; p.y = ss[0] + ss[1] + ss[2] + ss[3];
        partials[blockIdx.x] = p;
    }
}

// ---------------------------------------------------------------------------
// K2b: combine 64 partials per class -> (M, 1/S); zero Mbuf. 1 block x 256 thr.
// ---------------------------------------------------------------------------
__global__ __launch_bounds__(256)
void k2b_combine(const float2* __restrict__ partials, float2* __restrict__ MS,
                 float* __restrict__ Mbuf)
{
    const int tid = threadIdx.x;
    #pragma unroll
    for (int i = 0; i < 4; ++i) Mbuf[tid + 256 * i] = 0.f;
    if (tid < 128) {
        const int c = tid >> 6, lane = tid & 63;
        float2 p = partials[c * 64 + lane];
        float M = p.x;
        #pragma unroll
        for (int o = 1; o < 64; o <<= 1) M = fmaxf(M, __shfl_xor(M, o));
        float s = p.y * __expf(p.x - M);
        #pragma unroll
        for (int o = 1; o < 64; o <<= 1) s += __shfl_xor(s, o);
        if (lane == 0) { float2 r; r.x = M; r.y = 1.f / s; MS[c] = r; }
    }
}

// ---------------------------------------------------------------------------
// K3: fused normalize + pool. 1024 blocks x 256 thr.
// ---------------------------------------------------------------------------
__global__ __launch_bounds__(256)
void k3_pool(const float* __restrict__ A_logits, const float2* __restrict__ MS,
             const f16* __restrict__ hnew16, float* __restrict__ A_out,
             float* __restrict__ Mbuf)
{
    const int tid = threadIdx.x, lane = tid & 63, w = tid >> 6;
    const int per = (N_ROWS + gridDim.x - 1) / gridDim.x;
    const int r0 = blockIdx.x * per;
    const int r1 = min(r0 + per, N_ROWS);
    const float2 ms0 = MS[0], ms1 = MS[1];
    __shared__ float red[4][2][DIM];   // 16 KB

    float acc0[8], acc1[8];
    #pragma unroll
    for (int j = 0; j < 8; ++j) { acc0[j] = 0.f; acc1[j] = 0.f; }

    for (int n = r0 + w; n < r1; n += 4) {
        float w0 = __expf(A_logits[n]          - ms0.x) * ms0.y;
        float w1 = __expf(A_logits[N_ROWS + n] - ms1.x) * ms1.y;
        if (lane == 0)      A_out[n] = w0;
        else if (lane == 1) A_out[N_ROWS + n] = w1;
        f16x8 hv = *(const f16x8*)(hnew16 + (size_t)n * DIM + lane * 8);
        #pragma unroll
        for (int j = 0; j < 8; ++j) {
            float hx = (float)hv[j];
            acc0[j] += w0 * hx;
            acc1[j] += w1 * hx;
        }
    }
    #pragma unroll
    for (int j = 0; j < 8; ++j) {
        red[w][0][lane * 8 + j] = acc0[j];
        red[w][1][lane * 8 + j] = acc1[j];
    }
    __syncthreads();
    #pragma unroll
    for (int t = 0; t < 4; ++t) {
        int idx = tid + t * 256;              // 0..1023
        int c = idx >> 9, d = idx & 511;
        float s = red[0][c][d] + red[1][c][d] + red[2][c][d] + red[3][c][d];
        atomicAdd(&Mbuf[c * DIM + d], s);
    }
}

// ---------------------------------------------------------------------------
// K4: logits/softmax/argmax/features. Output layout (floats):
//   [0..1] logits, [2..3] Y_prob, [4] Y_hat, [5..200004] A, [200005..200516] features
// ---------------------------------------------------------------------------
__global__ __launch_bounds__(512)
void k4_final(const float* __restrict__ Mbuf,
              const float* __restrict__ Wclf, const float* __restrict__ bclf,
              float* __restrict__ out)
{
    __shared__ float red[16];
    const int tid  = threadIdx.x;
    const int lane = tid & 63;
    const int wid  = tid >> 6;

    float m0 = Mbuf[tid];
    float m1 = Mbuf[DIM + tid];
    float p0 = m0 * Wclf[tid];
    float p1 = m1 * Wclf[DIM + tid];
    #pragma unroll
    for (int o = 1; o < 64; o <<= 1) {
        p0 += __shfl_xor(p0, o);
        p1 += __shfl_xor(p1, o);
    }
    if (lane == 0) { red[wid] = p0; red[8 + wid] = p1; }
    __syncthreads();
    if (tid == 0) {
        float l0 = bclf[0], l1 = bclf[1];
        for (int ww = 0; ww < 8; ++ww) { l0 += red[ww]; l1 += red[8 + ww]; }
        out[0] = l0; out[1] = l1;
        float mx = fmaxf(l0, l1);
        float e0 = expf(l0 - mx), e1 = expf(l1 - mx);
        float inv = 1.f / (e0 + e1);
        out[2] = e0 * inv; out[3] = e1 * inv;
        out[4] = (l1 > l0) ? 1.0f : 0.0f;
    }
    out[5 + 2 * N_ROWS + tid] = m1;          // features = M[C-1][:]
}

// ---------------------------------------------------------------------------
extern "C" void kernel_launch(void* const* d_in, const int* in_sizes, int n_in,
                              void* d_out, int out_size, void* d_ws, size_t ws_size,
                              hipStream_t stream)
{
    const float* h    = (const float*)d_in[0];
    const float* W1   = (const float*)d_in[1];
    const float* b1   = (const float*)d_in[2];
    const float* W2   = (const float*)d_in[3];
    const float* b2   = (const float*)d_in[4];
    const float* Wa   = (const float*)d_in[5];
    const float* ba   = (const float*)d_in[6];
    const float* Wb   = (const float*)d_in[7];
    const float* bb   = (const float*)d_in[8];
    const float* Wc   = (const float*)d_in[9];
    const float* bc   = (const float*)d_in[10];
    const float* Wclf = (const float*)d_in[11];
    const float* bclf = (const float*)d_in[12];
    float* out = (float*)d_out;

    // workspace layout (all 16B-aligned)
    f16*    hnew16   = (f16*)d_ws;                                 // 102.4 MB
    f16*    W1f      = (f16*)((char*)d_ws + (size_t)N_ROWS * DIM * 2);
    f16*    W2f      = W1f + 256 * 512;
    f16*    Waf      = W2f + 512 * 256;
    f16*    Wbf      = Waf + 2 * 256 * 512;
    float*  A_logits = (float*)(Wbf + 2 * 256 * 512);              // 2*N f32
    float*  Mbuf     = A_logits + 2 * (size_t)N_ROWS;              // 1024 f32
    float2* partials = (float2*)(Mbuf + 1024);                     // 128 float2
    float2* MS       = partials + 2 * NCHUNK;                      // 2 float2
    float*  A_out    = out + 5;

    k0_cvt<<<768, 256, 0, stream>>>(W1, W2, Wa, Wb, W1f);
    k1_fused<<<N_ROWS / BN, 512, 0, stream>>>(h, W1f, b1, W2f, b2, Waf, ba,
                                              Wbf, bb, Wc, bc, hnew16, A_logits);
    k2a_partial<<<2 * NCHUNK, 256, 0, stream>>>(A_logits, partials);
    k2b_combine<<<1, 256, 0, stream>>>(partials, MS, Mbuf);
    k3_pool<<<1024, 256, 0, stream>>>(A_logits, MS, hnew16, A_out, Mbuf);
    k4_final<<<1, 512, 0, stream>>>(Mbuf, Wclf, bclf, out);
}

// Round 6
// 689.856 us; speedup vs baseline: 6.8536x; 1.0179x over previous
//
#include <hip/hip_runtime.h>
#include <math.h>

#define N_ROWS 100000
#define DIM    512
#define DHID   256
#define NCLS   2
#define BN     64   // rows per block in k1 (2 row-groups x 32)
#define NCHUNK 64   // softmax partial chunks per class

typedef _Float16 f16;
typedef __attribute__((ext_vector_type(8))) _Float16 f16x8;
typedef __attribute__((ext_vector_type(4))) _Float16 f16x4;
typedef __attribute__((ext_vector_type(2))) _Float16 f16x2;
typedef __attribute__((ext_vector_type(4))) float f32x4;

__device__ inline float frcp(float x){
#if __has_builtin(__builtin_amdgcn_rcpf)
    return __builtin_amdgcn_rcpf(x);
#else
    return 1.f / x;
#endif
}

// direct global->LDS DMA, 16B per lane (dest = wave-uniform base + lane*16)
__device__ __forceinline__ void gll16(const f16* g, f16* l) {
    __builtin_amdgcn_global_load_lds(
        (const __attribute__((address_space(1))) void*)g,
        (__attribute__((address_space(3))) void*)l, 16, 0, 0);
}

// ---------------------------------------------------------------------------
// K0: convert all GEMM weights fp32 -> fp16 into workspace.
// ---------------------------------------------------------------------------
__global__ __launch_bounds__(256)
void k0_cvt(const float* __restrict__ W1, const float* __restrict__ W2,
            const float* __restrict__ Wa, const float* __restrict__ Wb,
            f16* __restrict__ out)
{
    int i = (blockIdx.x * 256 + threadIdx.x) * 4;
    const float* src; int off;
    if      (i < 131072) { src = W1; off = 0; }
    else if (i < 262144) { src = W2; off = 131072; }
    else if (i < 524288) { src = Wa; off = 262144; }
    else                 { src = Wb; off = 524288; }
    float4 v = *(const float4*)(src + (i - off));
    f16x4 o; o[0] = (f16)v.x; o[1] = (f16)v.y; o[2] = (f16)v.z; o[3] = (f16)v.w;
    *(f16x4*)(out + i) = o;
}

// ---------------------------------------------------------------------------
// K1: fused MLP + gated attention logits, BN=64 rows/block, 8 waves arranged
// 2 row-groups x 4 col-groups. Per K-step per wave: 2 A ds_reads + 4 B
// ds_reads + 8 MFMA (R5 was 1:1 -> LDS-BW-bound; this is 1.33:1 and each
// staged W-slice serves 2x rows). Weights staged via global_load_lds dbuf.
// LDS: sh_h 64K + sh_hid 32K + wbuf 32K = 128K -> 1 block/CU.
// ---------------------------------------------------------------------------
#define MFMA(a,b,c) __builtin_amdgcn_mfma_f32_16x16x32_f16((a),(b),(c),0,0,0)

__global__ __launch_bounds__(512, 2)
void k1_fused(const float* __restrict__ h,
              const f16* __restrict__ W1f, const float* __restrict__ b1,
              const f16* __restrict__ W2f, const float* __restrict__ b2,
              const f16* __restrict__ Waf, const float* __restrict__ ba,
              const f16* __restrict__ Wbf, const float* __restrict__ bb,
              const float* __restrict__ Wc, const float* __restrict__ bc,
              f16* __restrict__ hnew16, float* __restrict__ A_logits)
{
    __shared__ __align__(16) f16 sh_h[BN * DIM];    // 64 KB swizzled; h then hnew
    __shared__ __align__(16) f16 sh_hid[BN * DHID]; // 32 KB swizzled
    __shared__ __align__(16) f16 sh_wb[16384];      // 32 KB: 2 x 16KB W-slice dbuf

    const int tid  = threadIdx.x;
    const int lane = tid & 63;
    const int w    = tid >> 6;     // wave 0..7
    const int l16  = lane & 15;
    const int grp  = lane >> 4;    // 0..3
    const int rg   = w >> 2;       // row-group 0..1 (rows rg*32..rg*32+31)
    const int cg   = w & 3;        // col-group 0..3 (cols cg*64..cg*64+63)
    const int n0   = blockIdx.x * BN;

    #define SWZH(row, col) ((row) * DIM  + ((col) ^ (((row) & 7) << 3)))
    #define SWZD(row, col) ((row) * DHID + ((col) ^ (((row) & 7) << 3)))

    // stage one 256-col x 32-k W-slice (16KB) into wbuf half `bufbase` (elems)
    #define STAGE_B(P, KROW, kb, bufbase)                                     \
    do {                                                                      \
        int u0 = tid;                                                         \
        int c0_ = u0 >> 2, ks0 = (u0 & 3) ^ ((u0 >> 3) & 3);                  \
        gll16((P) + (size_t)c0_ * (KROW) + (kb) + ks0 * 8,                    \
              &sh_wb[(bufbase) + u0 * 8]);                                    \
        int u1 = tid + 512;                                                   \
        int c1_ = u1 >> 2, ks1 = (u1 & 3) ^ ((u1 >> 3) & 3);                  \
        gll16((P) + (size_t)c1_ * (KROW) + (kb) + ks1 * 8,                    \
              &sh_wb[(bufbase) + u1 * 8]);                                    \
    } while (0)

    const int bslot = grp ^ ((l16 >> 1) & 3);   // read-side swizzle slot
    #define BFRAG(bufbase, T) \
        (*(const f16x8*)&sh_wb[(bufbase) + (((T) * 16 + l16) * 4 + bslot) * 8])

    // ---- Phase A: stage h (fp32 -> fp16, swizzled, row-clamped for tail) ----
    {
        #pragma unroll
        for (int i = 0; i < 8; ++i) {
            int cch = tid + 512 * i;              // 8-elem chunk id, 0..4095
            int row = cch >> 6, colb = (cch & 63) * 8;
            int g = n0 + row;
            const float4* hsrc = (const float4*)
                (h + (size_t)(g < N_ROWS ? g : N_ROWS - 1) * DIM + colb);
            float4 lo = hsrc[0], hi = hsrc[1];
            f16x8 v;
            v[0] = (f16)lo.x; v[1] = (f16)lo.y; v[2] = (f16)lo.z; v[3] = (f16)lo.w;
            v[4] = (f16)hi.x; v[5] = (f16)hi.y; v[6] = (f16)hi.z; v[7] = (f16)hi.w;
            *(f16x8*)&sh_h[SWZH(row, colb)] = v;
        }
    }
    STAGE_B(W1f, DIM, 0, 0);          // prologue for Phase B
    __syncthreads();

    // ---- Phase B: hid = relu(h @ W1^T + b1); 64r x 256c, K=512, 16 steps ----
    {
        f32x4 acc[2][4];
        #pragma unroll
        for (int m = 0; m < 2; ++m)
            #pragma unroll
            for (int q = 0; q < 4; ++q) acc[m][q] = (f32x4){0,0,0,0};
        #pragma unroll
        for (int kt = 0; kt < 16; ++kt) {
            const int bb = (kt & 1) * 8192;
            if (kt < 15) STAGE_B(W1f, DIM, (kt + 1) * 32, ((kt + 1) & 1) * 8192);
            else         STAGE_B(W2f, DHID, 0, 0);        // Phase C half0 prologue
            int kc = kt * 32 + grp * 8;
            f16x8 a0 = *(const f16x8*)&sh_h[SWZH(rg * 32 + l16,      kc)];
            f16x8 a1 = *(const f16x8*)&sh_h[SWZH(rg * 32 + 16 + l16, kc)];
            #pragma unroll
            for (int q = 0; q < 4; ++q) {
                f16x8 b = BFRAG(bb, cg * 4 + q);
                acc[0][q] = MFMA(a0, b, acc[0][q]);
                acc[1][q] = MFMA(a1, b, acc[1][q]);
            }
            __syncthreads();
        }
        #pragma unroll
        for (int q = 0; q < 4; ++q) {
            int col = (cg * 4 + q) * 16 + l16;
            float bias = b1[col];
            #pragma unroll
            for (int m = 0; m < 2; ++m)
                #pragma unroll
                for (int j = 0; j < 4; ++j) {
                    int row = rg * 32 + m * 16 + grp * 4 + j;
                    float v = acc[m][q][j] + bias;
                    sh_hid[SWZD(row, col)] = (f16)(v > 0.f ? v : 0.f);
                }
        }
        __syncthreads();
    }

    // ---- Phase C: hnew = h + hid @ W2^T + b2; 2 halves x 256c, K=256 ----
    #pragma unroll
    for (int half = 0; half < 2; ++half) {
        const f16* P = W2f + (size_t)half * 256 * DHID;
        f32x4 acc[2][4];
        #pragma unroll
        for (int m = 0; m < 2; ++m)
            #pragma unroll
            for (int q = 0; q < 4; ++q) acc[m][q] = (f32x4){0,0,0,0};
        #pragma unroll
        for (int kt = 0; kt < 8; ++kt) {
            const int bb = (kt & 1) * 8192;
            if (kt < 7)          STAGE_B(P, DHID, (kt + 1) * 32, ((kt + 1) & 1) * 8192);
            else if (half == 0)  STAGE_B(W2f + (size_t)256 * DHID, DHID, 0, 0);
            else                 STAGE_B(Waf, DIM, 0, 0);  // Phase D c0/Wa prologue
            int kc = kt * 32 + grp * 8;
            f16x8 a0 = *(const f16x8*)&sh_hid[SWZD(rg * 32 + l16,      kc)];
            f16x8 a1 = *(const f16x8*)&sh_hid[SWZD(rg * 32 + 16 + l16, kc)];
            #pragma unroll
            for (int q = 0; q < 4; ++q) {
                f16x8 b = BFRAG(bb, cg * 4 + q);
                acc[0][q] = MFMA(a0, b, acc[0][q]);
                acc[1][q] = MFMA(a1, b, acc[1][q]);
            }
            __syncthreads();
        }
        #pragma unroll
        for (int q = 0; q < 4; ++q) {
            int col = half * 256 + (cg * 4 + q) * 16 + l16;
            float bias = b2[col];
            #pragma unroll
            for (int m = 0; m < 2; ++m)
                #pragma unroll
                for (int j = 0; j < 4; ++j) {
                    int row = rg * 32 + m * 16 + grp * 4 + j;
                    int so  = SWZH(row, col);
                    float v = acc[m][q][j] + bias + (float)sh_h[so];
                    f16 hv = (f16)v;
                    sh_h[so] = hv;                   // element-exclusive in-place
                    int grow = n0 + row;
                    if (grow < N_ROWS) hnew16[(size_t)grow * DIM + col] = hv;
                }
        }
        __syncthreads();
    }

    // ---- Phase D: gated attention logits; per class: Wa pass + Wb pass ----
    float* sh_redf = (float*)&sh_wb[8192];   // alias wbuf[1] (barrier-separated)
    for (int c = 0; c < NCLS; ++c) {
        const f16* PA = Waf + (size_t)c * DHID * DIM;
        const f16* PB = Wbf + (size_t)c * DHID * DIM;
        f32x4 aA[2][4], aG[2][4];
        #pragma unroll
        for (int m = 0; m < 2; ++m)
            #pragma unroll
            for (int q = 0; q < 4; ++q) { aA[m][q] = (f32x4){0,0,0,0}; aG[m][q] = (f32x4){0,0,0,0}; }

        // pass 1: Wa (first slice staged by previous pass epilogue-slot)
        #pragma unroll
        for (int kt = 0; kt < 16; ++kt) {
            const int bb = (kt & 1) * 8192;
            if (kt < 15) STAGE_B(PA, DIM, (kt + 1) * 32, ((kt + 1) & 1) * 8192);
            else         STAGE_B(PB, DIM, 0, 0);          // Wb pass prologue
            int kc = kt * 32 + grp * 8;
            f16x8 a0 = *(const f16x8*)&sh_h[SWZH(rg * 32 + l16,      kc)];
            f16x8 a1 = *(const f16x8*)&sh_h[SWZH(rg * 32 + 16 + l16, kc)];
            #pragma unroll
            for (int q = 0; q < 4; ++q) {
                f16x8 b = BFRAG(bb, cg * 4 + q);
                aA[0][q] = MFMA(a0, b, aA[0][q]);
                aA[1][q] = MFMA(a1, b, aA[1][q]);
            }
            __syncthreads();
        }
        // pass 2: Wb
        #pragma unroll
        for (int kt = 0; kt < 16; ++kt) {
            const int bb = (kt & 1) * 8192;
            if (kt < 15)      STAGE_B(PB, DIM, (kt + 1) * 32, ((kt + 1) & 1) * 8192);
            else if (c == 0)  STAGE_B(Waf + (size_t)DHID * DIM, DIM, 0, 0); // class1 Wa
            int kc = kt * 32 + grp * 8;
            f16x8 a0 = *(const f16x8*)&sh_h[SWZH(rg * 32 + l16,      kc)];
            f16x8 a1 = *(const f16x8*)&sh_h[SWZH(rg * 32 + 16 + l16, kc)];
            #pragma unroll
            for (int q = 0; q < 4; ++q) {
                f16x8 b = BFRAG(bb, cg * 4 + q);
                aG[0][q] = MFMA(a0, b, aG[0][q]);
                aG[1][q] = MFMA(a1, b, aG[1][q]);
            }
            __syncthreads();
        }
        // epilogue: gate, weight by Wc, reduce 256 k-cols -> logit per row
        float vsum[2][4];
        #pragma unroll
        for (int m = 0; m < 2; ++m)
            #pragma unroll
            for (int j = 0; j < 4; ++j) vsum[m][j] = 0.f;
        #pragma unroll
        for (int q = 0; q < 4; ++q) {
            int col = (cg * 4 + q) * 16 + l16;
            float bav = ba[c * DHID + col];
            float bbv = bb[c * DHID + col];
            float wcv = Wc[c * DHID + col];
            #pragma unroll
            for (int m = 0; m < 2; ++m)
                #pragma unroll
                for (int j = 0; j < 4; ++j) {
                    float sa = aA[m][q][j] + bav;
                    float sg = aG[m][q][j] + bbv;
                    float ea = __expf(2.f * sa);
                    float ta = 1.f - 2.f * frcp(ea + 1.f);      // tanh
                    float sgm = frcp(1.f + __expf(-sg));        // sigmoid
                    vsum[m][j] += ta * sgm * wcv;
                }
        }
        #pragma unroll
        for (int m = 0; m < 2; ++m)
            #pragma unroll
            for (int j = 0; j < 4; ++j) {
                float v = vsum[m][j];
                v += __shfl_xor(v, 1); v += __shfl_xor(v, 2);
                v += __shfl_xor(v, 4); v += __shfl_xor(v, 8);
                if (l16 == 0) sh_redf[w * 32 + m * 16 + grp * 4 + j] = v;
            }
        __syncthreads();
        if (tid < BN) {
            int rg_ = tid >> 5, rloc = tid & 31;
            float s = bc[c];
            #pragma unroll
            for (int cgi = 0; cgi < 4; ++cgi)
                s += sh_redf[(rg_ * 4 + cgi) * 32 + rloc];
            int grow = n0 + tid;
            if (grow < N_ROWS) A_logits[(size_t)c * N_ROWS + grow] = s;
        }
        __syncthreads();
    }
    #undef SWZH
    #undef SWZD
    #undef STAGE_B
    #undef BFRAG
}

// ---------------------------------------------------------------------------
// K2a: per-chunk (class, chunk) partial max + expsum. 128 blocks x 256 thr.
// ---------------------------------------------------------------------------
__global__ __launch_bounds__(256)
void k2a_partial(const float* __restrict__ A_logits, float2* __restrict__ partials)
{
    const int c     = blockIdx.x >> 6;
    const int chunk = blockIdx.x & 63;
    const int per   = (N_ROWS + NCHUNK - 1) / NCHUNK;   // 1563
    const int i0 = chunk * per;
    const int i1 = min(i0 + per, N_ROWS);
    const int tid = threadIdx.x, lane = tid & 63, w = tid >> 6;
    const float* L = A_logits + (size_t)c * N_ROWS;
    __shared__ float sm[4], ss[4];

    float m = -1e30f;
    for (int i = i0 + tid; i < i1; i += 256) m = fmaxf(m, L[i]);
    #pragma unroll
    for (int o = 1; o < 64; o <<= 1) m = fmaxf(m, __shfl_xor(m, o));
    if (lane == 0) sm[w] = m;
    __syncthreads();
    m = fmaxf(fmaxf(sm[0], sm[1]), fmaxf(sm[2], sm[3]));

    float s = 0.f;
    for (int i = i0 + tid; i < i1; i += 256) s += __expf(L[i] - m);
    #pragma unroll
    for (int o = 1; o < 64; o <<= 1) s += __shfl_xor(s, o);
    if (lane == 0) ss[w] = s;
    __syncthreads();
    if (tid == 0) {
        float2 p; p.x = m; p.y = ss[0] + ss[1] + ss[2] + ss[3];
        partials[blockIdx.x] = p;
    }
}

// ---------------------------------------------------------------------------
// K2b: combine 64 partials per class -> (M, 1/S); zero Mbuf. 1 block x 256 thr.
// ---------------------------------------------------------------------------
__global__ __launch_bounds__(256)
void k2b_combine(const float2* __restrict__ partials, float2* __restrict__ MS,
                 float* __restrict__ Mbuf)
{
    const int tid = threadIdx.x;
    #pragma unroll
    for (int i = 0; i < 4; ++i) Mbuf[tid + 256 * i] = 0.f;
    if (tid < 128) {
        const int c = tid >> 6, lane = tid & 63;
        float2 p = partials[c * 64 + lane];
        float M = p.x;
        #pragma unroll
        for (int o = 1; o < 64; o <<= 1) M = fmaxf(M, __shfl_xor(M, o));
        float s = p.y * __expf(p.x - M);
        #pragma unroll
        for (int o = 1; o < 64; o <<= 1) s += __shfl_xor(s, o);
        if (lane == 0) { float2 r; r.x = M; r.y = 1.f / s; MS[c] = r; }
    }
}

// ---------------------------------------------------------------------------
// K3: fused normalize + pool. 1024 blocks x 256 thr.
// ---------------------------------------------------------------------------
__global__ __launch_bounds__(256)
void k3_pool(const float* __restrict__ A_logits, const float2* __restrict__ MS,
             const f16* __restrict__ hnew16, float* __restrict__ A_out,
             float* __restrict__ Mbuf)
{
    const int tid = threadIdx.x, lane = tid & 63, w = tid >> 6;
    const int per = (N_ROWS + gridDim.x - 1) / gridDim.x;
    const int r0 = blockIdx.x * per;
    const int r1 = min(r0 + per, N_ROWS);
    const float2 ms0 = MS[0], ms1 = MS[1];
    __shared__ float red[4][2][DIM];   // 16 KB

    float acc0[8], acc1[8];
    #pragma unroll
    for (int j = 0; j < 8; ++j) { acc0[j] = 0.f; acc1[j] = 0.f; }

    for (int n = r0 + w; n < r1; n += 4) {
        float w0 = __expf(A_logits[n]          - ms0.x) * ms0.y;
        float w1 = __expf(A_logits[N_ROWS + n] - ms1.x) * ms1.y;
        if (lane == 0)      A_out[n] = w0;
        else if (lane == 1) A_out[N_ROWS + n] = w1;
        f16x8 hv = *(const f16x8*)(hnew16 + (size_t)n * DIM + lane * 8);
        #pragma unroll
        for (int j = 0; j < 8; ++j) {
            float hx = (float)hv[j];
            acc0[j] += w0 * hx;
            acc1[j] += w1 * hx;
        }
    }
    #pragma unroll
    for (int j = 0; j < 8; ++j) {
        red[w][0][lane * 8 + j] = acc0[j];
        red[w][1][lane * 8 + j] = acc1[j];
    }
    __syncthreads();
    #pragma unroll
    for (int t = 0; t < 4; ++t) {
        int idx = tid + t * 256;              // 0..1023
        int c = idx >> 9, d = idx & 511;
        float s = red[0][c][d] + red[1][c][d] + red[2][c][d] + red[3][c][d];
        atomicAdd(&Mbuf[c * DIM + d], s);
    }
}

// ---------------------------------------------------------------------------
// K4: logits/softmax/argmax/features. Output layout (floats):
//   [0..1] logits, [2..3] Y_prob, [4] Y_hat, [5..200004] A, [200005..200516] features
// ---------------------------------------------------------------------------
__global__ __launch_bounds__(512)
void k4_final(const float* __restrict__ Mbuf,
              const float* __restrict__ Wclf, const float* __restrict__ bclf,
              float* __restrict__ out)
{
    __shared__ float red[16];
    const int tid  = threadIdx.x;
    const int lane = tid & 63;
    const int wid  = tid >> 6;

    float m0 = Mbuf[tid];
    float m1 = Mbuf[DIM + tid];
    float p0 = m0 * Wclf[tid];
    float p1 = m1 * Wclf[DIM + tid];
    #pragma unroll
    for (int o = 1; o < 64; o <<= 1) {
        p0 += __shfl_xor(p0, o);
        p1 += __shfl_xor(p1, o);
    }
    if (lane == 0) { red[wid] = p0; red[8 + wid] = p1; }
    __syncthreads();
    if (tid == 0) {
        float l0 = bclf[0], l1 = bclf[1];
        for (int ww = 0; ww < 8; ++ww) { l0 += red[ww]; l1 += red[8 + ww]; }
        out[0] = l0; out[1] = l1;
        float mx = fmaxf(l0, l1);
        float e0 = expf(l0 - mx), e1 = expf(l1 - mx);
        float inv = 1.f / (e0 + e1);
        out[2] = e0 * inv; out[3] = e1 * inv;
        out[4] = (l1 > l0) ? 1.0f : 0.0f;
    }
    out[5 + 2 * N_ROWS + tid] = m1;          // features = M[C-1][:]
}

// ---------------------------------------------------------------------------
extern "C" void kernel_launch(void* const* d_in, const int* in_sizes, int n_in,
                              void* d_out, int out_size, void* d_ws, size_t ws_size,
                              hipStream_t stream)
{
    const float* h    = (const float*)d_in[0];
    const float* W1   = (const float*)d_in[1];
    const float* b1   = (const float*)d_in[2];
    const float* W2   = (const float*)d_in[3];
    const float* b2   = (const float*)d_in[4];
    const float* Wa   = (const float*)d_in[5];
    const float* ba   = (const float*)d_in[6];
    const float* Wb   = (const float*)d_in[7];
    const float* bb   = (const float*)d_in[8];
    const float* Wc   = (const float*)d_in[9];
    const float* bc   = (const float*)d_in[10];
    const float* Wclf = (const float*)d_in[11];
    const float* bclf = (const float*)d_in[12];
    float* out = (float*)d_out;

    // workspace layout (all 16B-aligned)
    f16*    hnew16   = (f16*)d_ws;                                 // 102.4 MB
    f16*    W1f      = (f16*)((char*)d_ws + (size_t)N_ROWS * DIM * 2);
    f16*    W2f      = W1f + 256 * 512;
    f16*    Waf      = W2f + 512 * 256;
    f16*    Wbf      = Waf + 2 * 256 * 512;
    float*  A_logits = (float*)(Wbf + 2 * 256 * 512);              // 2*N f32
    float*  Mbuf     = A_logits + 2 * (size_t)N_ROWS;              // 1024 f32
    float2* partials = (float2*)(Mbuf + 1024);                     // 128 float2
    float2* MS       = partials + 2 * NCHUNK;                      // 2 float2
    float*  A_out    = out + 5;

    k0_cvt<<<768, 256, 0, stream>>>(W1, W2, Wa, Wb, W1f);
    k1_fused<<<(N_ROWS + BN - 1) / BN, 512, 0, stream>>>(h, W1f, b1, W2f, b2,
                                              Waf, ba, Wbf, bb, Wc, bc,
                                              hnew16, A_logits);
    k2a_partial<<<2 * NCHUNK, 256, 0, stream>>>(A_logits, partials);
    k2b_combine<<<1, 256, 0, stream>>>(partials, MS, Mbuf);
    k3_pool<<<1024, 256, 0, stream>>>(A_logits, MS, hnew16, A_out, Mbuf);
    k4_final<<<1, 512, 0, stream>>>(Mbuf, Wclf, bclf, out);
}